// Round 4
// baseline (568.601 us; speedup 1.0000x reference)
//
#include <hip/hip_runtime.h>

// ---------------------------------------------------------------------------
// GCN 2-layer fused pipeline for MI355X (gfx950)
//   h1 = relu(Dinv (A+I) Dinv (x@W1) + b1)
//   out = 0.5*(h1@Wc + bc) + 0.5*((alpha*h2 + (1-alpha)*h1)@Wf + bf)
//   h2 = relu(Dinv (A+I) Dinv (h1@W2) + b2)
// R2: binned counting-sort CSR build (no scattered-atomic writes).
// R3: aggs were latency-bound (VGPR=12 -> MLP~2, VALUBusy 31%). Now:
//     (a) explicit 8-deep row-gather prefetch in agg1/agg2;
//     (b) colv2 = {src, dinv[src]} packed at fine_kernel time, removing the
//         per-edge dinv gather + one shuffle from the hot loop.
// ---------------------------------------------------------------------------

#define HID 128
#define SHIFT 9
#define RANGE 512           // nodes per bin = 1<<SHIFT
#define MAXB 256            // max bins (N <= 131072)
#define TILE 4096           // edges per stage block

typedef __bf16 bf16x8 __attribute__((ext_vector_type(8)));
typedef float  f32x4  __attribute__((ext_vector_type(4)));

__device__ __forceinline__ unsigned short f2bf(float x) {
    unsigned int b = __float_as_uint(x);
    b += 0x7fffu + ((b >> 16) & 1u);     // round-to-nearest-even
    return (unsigned short)(b >> 16);
}
__device__ __forceinline__ float bflo(unsigned int u) { return __uint_as_float(u << 16); }
__device__ __forceinline__ float bfhi(unsigned int u) { return __uint_as_float(u & 0xffff0000u); }

// --------------------------- binned CSR build ------------------------------

__global__ __launch_bounds__(256)
void bincount_kernel(const int* __restrict__ dst, int* __restrict__ bin_counts,
                     int E, int NB) {
    __shared__ int h[MAXB];
    for (int i = threadIdx.x; i < NB; i += 256) h[i] = 0;
    __syncthreads();
    const int base = blockIdx.x * TILE;
#pragma unroll
    for (int j = 0; j < TILE; j += 256) {
        int e = base + j + threadIdx.x;
        if (e < E) atomicAdd(&h[((unsigned)dst[e]) >> SHIFT], 1);
    }
    __syncthreads();
    for (int i = threadIdx.x; i < NB; i += 256) {
        int v = h[i];
        if (v) atomicAdd(&bin_counts[i], v);
    }
}

__global__ void binscan_kernel(const int* __restrict__ bin_counts,
                               int* __restrict__ bin_off, int* __restrict__ bin_cur, int NB) {
    __shared__ int sh[MAXB];
    const int t = threadIdx.x;
    int v = (t < NB) ? bin_counts[t] : 0;
    sh[t] = v;
    __syncthreads();
    for (int s = 1; s < 256; s <<= 1) {
        int x = (t >= s) ? sh[t - s] : 0;
        __syncthreads();
        sh[t] += x;
        __syncthreads();
    }
    if (t < NB) {
        int ex = sh[t] - v;     // exclusive
        bin_off[t] = ex;
        bin_cur[t] = ex;
    }
}

// Block-level binning: tile-local LDS sort by bin, then bin-sorted write-out
// in contiguous runs. pairs[i] = (dlocal<<23) | src   (src < 2^23).
__global__ __launch_bounds__(256)
void stage_kernel(const int* __restrict__ src, const int* __restrict__ dst,
                  int* __restrict__ bin_cur, unsigned* __restrict__ pairs, int E) {
    __shared__ int sh_hist[MAXB];
    __shared__ int sh_off[MAXB];
    __shared__ int sh_ex[MAXB];
    __shared__ int sh_gbase[MAXB];
    __shared__ uint2 stg[TILE];
    const int t = threadIdx.x;
    const int base = blockIdx.x * TILE;
    const int cnt = min(TILE, E - base);

    for (int i = t; i < MAXB; i += 256) sh_hist[i] = 0;
    __syncthreads();

    int s[16], d[16], r[16];
#pragma unroll
    for (int j = 0; j < 16; ++j) {
        const int k = j * 256 + t;
        if (k < cnt) {
            s[j] = src[base + k];
            d[j] = dst[base + k];
            r[j] = atomicAdd(&sh_hist[((unsigned)d[j]) >> SHIFT], 1);
        }
    }
    __syncthreads();

    const int hv = sh_hist[t];
    sh_off[t] = hv;
    __syncthreads();
    for (int st = 1; st < 256; st <<= 1) {
        int x = (t >= st) ? sh_off[t - st] : 0;
        __syncthreads();
        sh_off[t] += x;
        __syncthreads();
    }
    sh_ex[t] = sh_off[t] - hv;                      // exclusive within tile
    if (hv > 0) sh_gbase[t] = atomicAdd(&bin_cur[t], hv);
    __syncthreads();

#pragma unroll
    for (int j = 0; j < 16; ++j) {
        const int k = j * 256 + t;
        if (k < cnt) {
            int b = ((unsigned)d[j]) >> SHIFT;
            stg[sh_ex[b] + r[j]] = make_uint2((unsigned)s[j], (unsigned)d[j]);
        }
    }
    __syncthreads();

    for (int i = t; i < cnt; i += 256) {
        uint2 p = stg[i];
        int b = (int)(p.y >> SHIFT);
        unsigned w = ((p.y & (RANGE - 1)) << 23) | p.x;
        pairs[sh_gbase[b] + (i - sh_ex[b])] = w;
    }
}

// Per-bin node in-degree counts via LDS
__global__ __launch_bounds__(256)
void nodecount_kernel(const unsigned* __restrict__ pairs, const int* __restrict__ bin_off,
                      int* __restrict__ counts, int N, int NB, int E) {
    __shared__ int c[RANGE];
    const int b = blockIdx.x;
    const int nb = b << SHIFT;
    const int nr = min(RANGE, N - nb);
    for (int i = threadIdx.x; i < nr; i += 256) c[i] = 0;
    __syncthreads();
    const int lo = bin_off[b];
    const int hi = (b + 1 < NB) ? bin_off[b + 1] : E;
    for (int i = lo + threadIdx.x; i < hi; i += 256)
        atomicAdd(&c[pairs[i] >> 23], 1);
    __syncthreads();
    for (int i = threadIdx.x; i < nr; i += 256) counts[nb + i] = c[i];
}

// Per-bin fine scatter; emits {src, dinv[src]} so aggs need no dinv gather
__global__ __launch_bounds__(256)
void fine_kernel(const unsigned* __restrict__ pairs, const int* __restrict__ bin_off,
                 const int* __restrict__ rowp, const float* __restrict__ dinv,
                 uint2* __restrict__ colv2, int N, int NB, int E) {
    __shared__ int cur[RANGE];
    const int b = blockIdx.x;
    const int nb = b << SHIFT;
    const int nr = min(RANGE, N - nb);
    for (int i = threadIdx.x; i < nr; i += 256) cur[i] = rowp[nb + i];
    __syncthreads();
    const int lo = bin_off[b];
    const int hi = (b + 1 < NB) ? bin_off[b + 1] : E;
    for (int i = lo + threadIdx.x; i < hi; i += 256) {
        unsigned w = pairs[i];
        unsigned s = w & 0x7fffffu;
        int pos = atomicAdd(&cur[w >> 23], 1);
        colv2[pos] = make_uint2(s, __float_as_uint(dinv[s]));
    }
}

// ----------------------- degree / scan -------------------------------------

__global__ void dinv_kernel(const int* __restrict__ counts, float* __restrict__ dinv, int n) {
    int i = blockIdx.x * 256 + threadIdx.x;
    if (i < n) dinv[i] = rsqrtf((float)(counts[i] + 1));   // +1 self-loop
}

__global__ __launch_bounds__(256)
void scan1_kernel(const int* __restrict__ counts, int* __restrict__ rowp1,
                  int* __restrict__ partials, int n) {
    __shared__ int sh[256];
    const int t = threadIdx.x;
    const int base = blockIdx.x * 1024 + t * 4;
    int v0 = (base     < n) ? counts[base]     : 0;
    int v1 = (base + 1 < n) ? counts[base + 1] : 0;
    int v2 = (base + 2 < n) ? counts[base + 2] : 0;
    int v3 = (base + 3 < n) ? counts[base + 3] : 0;
    v1 += v0; v2 += v1; v3 += v2;
    sh[t] = v3;
    __syncthreads();
    for (int off = 1; off < 256; off <<= 1) {
        int x = (t >= off) ? sh[t - off] : 0;
        __syncthreads();
        sh[t] += x;
        __syncthreads();
    }
    const int prefix = sh[t] - v3;
    if (base     < n) rowp1[base]     = prefix + v0;
    if (base + 1 < n) rowp1[base + 1] = prefix + v1;
    if (base + 2 < n) rowp1[base + 2] = prefix + v2;
    if (base + 3 < n) rowp1[base + 3] = prefix + v3;
    if (t == 255) partials[blockIdx.x] = sh[255];
}

__global__ void scan2_kernel(int* partials, int nchunks) {
    if (threadIdx.x == 0 && blockIdx.x == 0) {
        int run = 0;
        for (int i = 0; i < nchunks; ++i) { int t = partials[i]; partials[i] = run; run += t; }
    }
}

__global__ void scan3_kernel(int* __restrict__ rowp, const int* __restrict__ partials, int n) {
    int i = blockIdx.x * 256 + threadIdx.x;
    if (i < n) rowp[1 + i] += partials[i >> 10];
    if (i == 0) rowp[0] = 0;
}

// W (K x 128, row-major fp32) -> Wt (128 x K, bf16)
__global__ void wtprep_kernel(const float* __restrict__ W, unsigned short* __restrict__ Wt, int K) {
    int idx = blockIdx.x * 256 + threadIdx.x;
    if (idx < 128 * K) {
        int nn = idx / K, k = idx - nn * K;
        Wt[(size_t)nn * K + k] = f2bf(W[(size_t)k * 128 + nn]);
    }
}

// ------------------------------- GEMM --------------------------------------
template <bool A_BF16>
__global__ __launch_bounds__(256)
void gemm_kernel(const void* __restrict__ Aptr, const unsigned short* __restrict__ Wt,
                 unsigned short* __restrict__ Out, int nrows, int K) {
    const int tid  = threadIdx.x;
    const int wave = tid >> 6;
    const int lane = tid & 63;
    const int q = lane >> 4;
    const int r = lane & 15;
    const int wrow = blockIdx.x * 128 + wave * 32;

    f32x4 acc[2][8];
#pragma unroll
    for (int s = 0; s < 2; ++s)
#pragma unroll
        for (int c = 0; c < 8; ++c) acc[s][c] = (f32x4){0.f, 0.f, 0.f, 0.f};

    for (int k0 = 0; k0 < K; k0 += 32) {
        const int kk = k0 + q * 8;
        bf16x8 afrag[2];
#pragma unroll
        for (int s = 0; s < 2; ++s) {
            const int row = wrow + s * 16 + r;
            if (row < nrows) {
                if (A_BF16) {
                    afrag[s] = *reinterpret_cast<const bf16x8*>(
                        reinterpret_cast<const unsigned short*>(Aptr) + (size_t)row * K + kk);
                } else {
                    const float* ap = reinterpret_cast<const float*>(Aptr) + (size_t)row * K + kk;
                    const float4 x0 = *reinterpret_cast<const float4*>(ap);
                    const float4 x1 = *reinterpret_cast<const float4*>(ap + 4);
                    bf16x8 a;
                    a[0] = (__bf16)x0.x; a[1] = (__bf16)x0.y; a[2] = (__bf16)x0.z; a[3] = (__bf16)x0.w;
                    a[4] = (__bf16)x1.x; a[5] = (__bf16)x1.y; a[6] = (__bf16)x1.z; a[7] = (__bf16)x1.w;
                    afrag[s] = a;
                }
            } else {
                bf16x8 a;
#pragma unroll
                for (int j = 0; j < 8; ++j) a[j] = (__bf16)0.f;
                afrag[s] = a;
            }
        }
#pragma unroll
        for (int c = 0; c < 8; ++c) {
            const bf16x8 b = *reinterpret_cast<const bf16x8*>(Wt + (size_t)(c * 16 + r) * K + kk);
#pragma unroll
            for (int s = 0; s < 2; ++s)
                acc[s][c] = __builtin_amdgcn_mfma_f32_16x16x32_bf16(afrag[s], b, acc[s][c], 0, 0, 0);
        }
    }
#pragma unroll
    for (int s = 0; s < 2; ++s)
#pragma unroll
        for (int v = 0; v < 4; ++v) {
            const int row = wrow + s * 16 + q * 4 + v;
            if (row < nrows) {
#pragma unroll
                for (int c = 0; c < 8; ++c)
                    Out[(size_t)row * 128 + c * 16 + r] = f2bf(acc[s][c][v]);
            }
        }
}

// --------------------------- Aggregation -----------------------------------
// One wave per node; lane l owns features 2l, 2l+1 (packed uint of 2 bf16).
// 8-deep explicit prefetch of gathered rows for memory-level parallelism.

#define GATHER_CHUNK(ACC0, ACC1)                                               \
    for (int base = beg; base < end; base += 64) {                             \
        const int e = base + lane;                                             \
        int s = 0; float w = 0.f;                                              \
        if (e < end) { uint2 cw = colv2[e]; s = (int)cw.x;                     \
                       w = __uint_as_float(cw.y); }                            \
        const int cnt = min(64, end - base);                                   \
        for (int t = 0; t < cnt; t += 8) {                                     \
            const int m = min(8, cnt - t);                                     \
            unsigned uu[8];                                                    \
            _Pragma("unroll")                                                  \
            for (int k = 0; k < 8; ++k)                                        \
                if (k < m) {                                                   \
                    const int st = __shfl(s, t + k);                           \
                    uu[k] = xrow[(size_t)st * 64 + lane];                      \
                }                                                              \
            _Pragma("unroll")                                                  \
            for (int k = 0; k < 8; ++k)                                        \
                if (k < m) {                                                   \
                    const float wt = __shfl(w, t + k);                         \
                    ACC0 += bflo(uu[k]) * wt;                                  \
                    ACC1 += bfhi(uu[k]) * wt;                                  \
                }                                                              \
        }                                                                      \
    }

__global__ __launch_bounds__(256)
void agg1_kernel(const unsigned short* __restrict__ xw, const uint2* __restrict__ colv2,
                 const int* __restrict__ rowp, const float* __restrict__ dinv,
                 const float* __restrict__ b1, const float* __restrict__ Wc,
                 const float* __restrict__ bc, unsigned short* __restrict__ h1,
                 float* __restrict__ outp, int n) {
    const int node = blockIdx.x * 4 + (threadIdx.x >> 6);
    if (node >= n) return;
    const int lane = threadIdx.x & 63;
    const float di = dinv[node];
    const unsigned int* xrow = reinterpret_cast<const unsigned int*>(xw);

    unsigned int u = xrow[(size_t)node * 64 + lane];
    float acc0 = bflo(u) * di;
    float acc1 = bfhi(u) * di;

    const int beg = rowp[node], end = rowp[node + 1];
    GATHER_CHUNK(acc0, acc1)

    acc0 = fmaxf(acc0 * di + b1[2 * lane], 0.f);
    acc1 = fmaxf(acc1 * di + b1[2 * lane + 1], 0.f);

    reinterpret_cast<unsigned int*>(h1)[(size_t)node * 64 + lane] =
        (unsigned int)f2bf(acc0) | ((unsigned int)f2bf(acc1) << 16);

    float c0 = acc0 * Wc[4 * lane]     + acc1 * Wc[4 * lane + 2];
    float c1 = acc0 * Wc[4 * lane + 1] + acc1 * Wc[4 * lane + 3];
#pragma unroll
    for (int off = 32; off; off >>= 1) {
        c0 += __shfl_down(c0, off);
        c1 += __shfl_down(c1, off);
    }
    if (lane == 0) {
        outp[2 * (size_t)node]     = 0.5f * (c0 + bc[0]);
        outp[2 * (size_t)node + 1] = 0.5f * (c1 + bc[1]);
    }
}

__global__ __launch_bounds__(256)
void agg2_kernel(const unsigned short* __restrict__ xw2, const unsigned short* __restrict__ h1,
                 const uint2* __restrict__ colv2, const int* __restrict__ rowp,
                 const float* __restrict__ dinv, const float* __restrict__ b2,
                 const float* __restrict__ Wf, const float* __restrict__ bfv,
                 const float* __restrict__ hnode, float* __restrict__ outp, int n) {
    const int node = blockIdx.x * 4 + (threadIdx.x >> 6);
    if (node >= n) return;
    const int lane = threadIdx.x & 63;
    const float di = dinv[node];
    const unsigned int* xrow = reinterpret_cast<const unsigned int*>(xw2);

    unsigned int u = xrow[(size_t)node * 64 + lane];
    float acc0 = bflo(u) * di;
    float acc1 = bfhi(u) * di;

    const int beg = rowp[node], end = rowp[node + 1];
    GATHER_CHUNK(acc0, acc1)

    float h20 = fmaxf(acc0 * di + b2[2 * lane], 0.f);
    float h21 = fmaxf(acc1 * di + b2[2 * lane + 1], 0.f);

    const float alpha = hnode[node];
    const unsigned int hu = reinterpret_cast<const unsigned int*>(h1)[(size_t)node * 64 + lane];
    const float ha0 = alpha * h20 + (1.f - alpha) * bflo(hu);
    const float ha1 = alpha * h21 + (1.f - alpha) * bfhi(hu);

    float f0 = ha0 * Wf[4 * lane]     + ha1 * Wf[4 * lane + 2];
    float f1 = ha0 * Wf[4 * lane + 1] + ha1 * Wf[4 * lane + 3];
#pragma unroll
    for (int off = 32; off; off >>= 1) {
        f0 += __shfl_down(f0, off);
        f1 += __shfl_down(f1, off);
    }
    if (lane == 0) {
        outp[2 * (size_t)node]     += 0.5f * (f0 + bfv[0]);
        outp[2 * (size_t)node + 1] += 0.5f * (f1 + bfv[1]);
    }
}

// ------------------------------ launch -------------------------------------

extern "C" void kernel_launch(void* const* d_in, const int* in_sizes, int n_in,
                              void* d_out, int out_size, void* d_ws, size_t ws_size,
                              hipStream_t stream) {
    const float* x     = (const float*)d_in[0];
    const int*   ei    = (const int*)d_in[1];     // int32 per harness contract
    const float* hnode = (const float*)d_in[2];
    const float* W1    = (const float*)d_in[3];
    const float* b1    = (const float*)d_in[4];
    const float* W2    = (const float*)d_in[5];
    const float* b2    = (const float*)d_in[6];
    const float* Wc    = (const float*)d_in[7];
    const float* bc    = (const float*)d_in[8];
    const float* Wf    = (const float*)d_in[9];
    const float* bfv   = (const float*)d_in[10];

    const int N  = in_sizes[2];
    const int E  = in_sizes[1] / 2;
    const int K1 = in_sizes[3] / HID;   // 256
    const int NB = (N + RANGE - 1) >> SHIFT;
    const int* srcv = ei;
    const int* dstv = ei + E;
    float* outp = (float*)d_out;

    char* ws = (char*)d_ws;
    size_t off = 0;
    auto alloc = [&](size_t bytes) -> char* {
        char* p = ws + off;
        off += (bytes + 255) & ~(size_t)255;
        return p;
    };
    unsigned short* xw       = (unsigned short*)alloc((size_t)N * HID * 2);  // 25.6 MB
    unsigned short* h1       = (unsigned short*)alloc((size_t)N * HID * 2);  // 25.6 MB
    float*          dinv     = (float*)alloc((size_t)N * 4);
    int*            counts   = (int*)alloc((size_t)N * 4);
    int*            rowp     = (int*)alloc((size_t)(N + 1) * 4);
    uint2*          colv2    = (uint2*)alloc((size_t)E * 8);                 // 12.8 MB
    unsigned*       pairs    = (unsigned*)alloc((size_t)E * 4);              // 6.4 MB
    int*            bin_counts = (int*)alloc(MAXB * 4);
    int*            bin_off    = (int*)alloc(MAXB * 4);
    int*            bin_cur    = (int*)alloc(MAXB * 4);
    int*            partials   = (int*)alloc(4096);
    unsigned short* wt1      = (unsigned short*)alloc((size_t)HID * K1 * 2);
    unsigned short* wt2      = (unsigned short*)alloc((size_t)HID * HID * 2);

    hipMemsetAsync(bin_counts, 0, MAXB * 4, stream);
    wtprep_kernel<<<(HID * K1 + 255) / 256, 256, 0, stream>>>(W1, wt1, K1);
    wtprep_kernel<<<(HID * HID + 255) / 256, 256, 0, stream>>>(W2, wt2, HID);

    const int ntiles = (E + TILE - 1) / TILE;
    bincount_kernel<<<ntiles, 256, 0, stream>>>(dstv, bin_counts, E, NB);
    binscan_kernel<<<1, 256, 0, stream>>>(bin_counts, bin_off, bin_cur, NB);
    stage_kernel<<<ntiles, 256, 0, stream>>>(srcv, dstv, bin_cur, pairs, E);
    nodecount_kernel<<<NB, 256, 0, stream>>>(pairs, bin_off, counts, N, NB, E);
    dinv_kernel<<<(N + 255) / 256, 256, 0, stream>>>(counts, dinv, N);

    const int nchunks = (N + 1023) / 1024;
    scan1_kernel<<<nchunks, 256, 0, stream>>>(counts, rowp + 1, partials, N);
    scan2_kernel<<<1, 64, 0, stream>>>(partials, nchunks);
    scan3_kernel<<<(N + 255) / 256, 256, 0, stream>>>(rowp, partials, N);
    fine_kernel<<<NB, 256, 0, stream>>>(pairs, bin_off, rowp, dinv, colv2, N, NB, E);

    gemm_kernel<false><<<(N + 127) / 128, 256, 0, stream>>>((const void*)x, wt1, xw, N, K1);
    agg1_kernel<<<(N + 3) / 4, 256, 0, stream>>>(xw, colv2, rowp, dinv, b1, Wc, bc, h1, outp, N);
    gemm_kernel<true><<<(N + 127) / 128, 256, 0, stream>>>((const void*)h1, wt2, xw, N, HID);
    agg2_kernel<<<(N + 3) / 4, 256, 0, stream>>>(xw, h1, colv2, rowp, dinv, b2, Wf, bfv, hnode, outp, N);
}

// Round 5
// 490.725 us; speedup vs baseline: 1.1587x; 1.1587x over previous
//
#include <hip/hip_runtime.h>

// ---------------------------------------------------------------------------
// GCN 2-layer fused pipeline for MI355X (gfx950)
//   h1 = relu(Dinv (A+I) Dinv (x@W1) + b1)
//   out = 0.5*(h1@Wc + bc) + 0.5*((alpha*h2 + (1-alpha)*h1)@Wf + bf)
//   h2 = relu(Dinv (A+I) Dinv (h1@W2) + b2)
// R2: binned counting-sort CSR build (no scattered-atomic writes).
// R3: colv2 = {src, dinv[src]} fused at CSR build.
// R4 FAILED: 8-deep prefetch macro (+VALU, no MLP gain) -> reverted.
// R5: two-edge-per-wave dwordx2 gather: lane owns 4 features (uint2=4 bf16),
//     halves of the wave process 2 edges concurrently. ~7 wave-instr/edge vs
//     ~11, and half the gather instructions. Cross-half shfl_xor(32) merge
//     before the nonlinear epilogue.
// ---------------------------------------------------------------------------

#define HID 128
#define SHIFT 9
#define RANGE 512           // nodes per bin = 1<<SHIFT
#define MAXB 256            // max bins (N <= 131072)
#define TILE 4096           // edges per stage block

typedef __bf16 bf16x8 __attribute__((ext_vector_type(8)));
typedef float  f32x4  __attribute__((ext_vector_type(4)));

__device__ __forceinline__ unsigned short f2bf(float x) {
    unsigned int b = __float_as_uint(x);
    b += 0x7fffu + ((b >> 16) & 1u);     // round-to-nearest-even
    return (unsigned short)(b >> 16);
}
__device__ __forceinline__ float bflo(unsigned int u) { return __uint_as_float(u << 16); }
__device__ __forceinline__ float bfhi(unsigned int u) { return __uint_as_float(u & 0xffff0000u); }
__device__ __forceinline__ unsigned packbf(float a, float b) {
    return (unsigned)f2bf(a) | ((unsigned)f2bf(b) << 16);
}

// --------------------------- binned CSR build ------------------------------

__global__ __launch_bounds__(256)
void bincount_kernel(const int* __restrict__ dst, int* __restrict__ bin_counts,
                     int E, int NB) {
    __shared__ int h[MAXB];
    for (int i = threadIdx.x; i < NB; i += 256) h[i] = 0;
    __syncthreads();
    const int base = blockIdx.x * TILE;
#pragma unroll
    for (int j = 0; j < TILE; j += 256) {
        int e = base + j + threadIdx.x;
        if (e < E) atomicAdd(&h[((unsigned)dst[e]) >> SHIFT], 1);
    }
    __syncthreads();
    for (int i = threadIdx.x; i < NB; i += 256) {
        int v = h[i];
        if (v) atomicAdd(&bin_counts[i], v);
    }
}

__global__ void binscan_kernel(const int* __restrict__ bin_counts,
                               int* __restrict__ bin_off, int* __restrict__ bin_cur, int NB) {
    __shared__ int sh[MAXB];
    const int t = threadIdx.x;
    int v = (t < NB) ? bin_counts[t] : 0;
    sh[t] = v;
    __syncthreads();
    for (int s = 1; s < 256; s <<= 1) {
        int x = (t >= s) ? sh[t - s] : 0;
        __syncthreads();
        sh[t] += x;
        __syncthreads();
    }
    if (t < NB) {
        int ex = sh[t] - v;     // exclusive
        bin_off[t] = ex;
        bin_cur[t] = ex;
    }
}

// Block-level binning: tile-local LDS sort by bin, then bin-sorted write-out
// in contiguous runs. pairs[i] = (dlocal<<23) | src   (src < 2^23).
__global__ __launch_bounds__(256)
void stage_kernel(const int* __restrict__ src, const int* __restrict__ dst,
                  int* __restrict__ bin_cur, unsigned* __restrict__ pairs, int E) {
    __shared__ int sh_hist[MAXB];
    __shared__ int sh_off[MAXB];
    __shared__ int sh_ex[MAXB];
    __shared__ int sh_gbase[MAXB];
    __shared__ uint2 stg[TILE];
    const int t = threadIdx.x;
    const int base = blockIdx.x * TILE;
    const int cnt = min(TILE, E - base);

    for (int i = t; i < MAXB; i += 256) sh_hist[i] = 0;
    __syncthreads();

    int s[16], d[16], r[16];
#pragma unroll
    for (int j = 0; j < 16; ++j) {
        const int k = j * 256 + t;
        if (k < cnt) {
            s[j] = src[base + k];
            d[j] = dst[base + k];
            r[j] = atomicAdd(&sh_hist[((unsigned)d[j]) >> SHIFT], 1);
        }
    }
    __syncthreads();

    const int hv = sh_hist[t];
    sh_off[t] = hv;
    __syncthreads();
    for (int st = 1; st < 256; st <<= 1) {
        int x = (t >= st) ? sh_off[t - st] : 0;
        __syncthreads();
        sh_off[t] += x;
        __syncthreads();
    }
    sh_ex[t] = sh_off[t] - hv;                      // exclusive within tile
    if (hv > 0) sh_gbase[t] = atomicAdd(&bin_cur[t], hv);
    __syncthreads();

#pragma unroll
    for (int j = 0; j < 16; ++j) {
        const int k = j * 256 + t;
        if (k < cnt) {
            int b = ((unsigned)d[j]) >> SHIFT;
            stg[sh_ex[b] + r[j]] = make_uint2((unsigned)s[j], (unsigned)d[j]);
        }
    }
    __syncthreads();

    for (int i = t; i < cnt; i += 256) {
        uint2 p = stg[i];
        int b = (int)(p.y >> SHIFT);
        unsigned w = ((p.y & (RANGE - 1)) << 23) | p.x;
        pairs[sh_gbase[b] + (i - sh_ex[b])] = w;
    }
}

// Per-bin node in-degree counts via LDS
__global__ __launch_bounds__(256)
void nodecount_kernel(const unsigned* __restrict__ pairs, const int* __restrict__ bin_off,
                      int* __restrict__ counts, int N, int NB, int E) {
    __shared__ int c[RANGE];
    const int b = blockIdx.x;
    const int nb = b << SHIFT;
    const int nr = min(RANGE, N - nb);
    for (int i = threadIdx.x; i < nr; i += 256) c[i] = 0;
    __syncthreads();
    const int lo = bin_off[b];
    const int hi = (b + 1 < NB) ? bin_off[b + 1] : E;
    for (int i = lo + threadIdx.x; i < hi; i += 256)
        atomicAdd(&c[pairs[i] >> 23], 1);
    __syncthreads();
    for (int i = threadIdx.x; i < nr; i += 256) counts[nb + i] = c[i];
}

// Per-bin fine scatter; emits {src, dinv[src]} so aggs need no dinv gather
__global__ __launch_bounds__(256)
void fine_kernel(const unsigned* __restrict__ pairs, const int* __restrict__ bin_off,
                 const int* __restrict__ rowp, const float* __restrict__ dinv,
                 uint2* __restrict__ colv2, int N, int NB, int E) {
    __shared__ int cur[RANGE];
    const int b = blockIdx.x;
    const int nb = b << SHIFT;
    const int nr = min(RANGE, N - nb);
    for (int i = threadIdx.x; i < nr; i += 256) cur[i] = rowp[nb + i];
    __syncthreads();
    const int lo = bin_off[b];
    const int hi = (b + 1 < NB) ? bin_off[b + 1] : E;
    for (int i = lo + threadIdx.x; i < hi; i += 256) {
        unsigned w = pairs[i];
        unsigned s = w & 0x7fffffu;
        int pos = atomicAdd(&cur[w >> 23], 1);
        colv2[pos] = make_uint2(s, __float_as_uint(dinv[s]));
    }
}

// ----------------------- degree / scan -------------------------------------

__global__ void dinv_kernel(const int* __restrict__ counts, float* __restrict__ dinv, int n) {
    int i = blockIdx.x * 256 + threadIdx.x;
    if (i < n) dinv[i] = rsqrtf((float)(counts[i] + 1));   // +1 self-loop
}

__global__ __launch_bounds__(256)
void scan1_kernel(const int* __restrict__ counts, int* __restrict__ rowp1,
                  int* __restrict__ partials, int n) {
    __shared__ int sh[256];
    const int t = threadIdx.x;
    const int base = blockIdx.x * 1024 + t * 4;
    int v0 = (base     < n) ? counts[base]     : 0;
    int v1 = (base + 1 < n) ? counts[base + 1] : 0;
    int v2 = (base + 2 < n) ? counts[base + 2] : 0;
    int v3 = (base + 3 < n) ? counts[base + 3] : 0;
    v1 += v0; v2 += v1; v3 += v2;
    sh[t] = v3;
    __syncthreads();
    for (int off = 1; off < 256; off <<= 1) {
        int x = (t >= off) ? sh[t - off] : 0;
        __syncthreads();
        sh[t] += x;
        __syncthreads();
    }
    const int prefix = sh[t] - v3;
    if (base     < n) rowp1[base]     = prefix + v0;
    if (base + 1 < n) rowp1[base + 1] = prefix + v1;
    if (base + 2 < n) rowp1[base + 2] = prefix + v2;
    if (base + 3 < n) rowp1[base + 3] = prefix + v3;
    if (t == 255) partials[blockIdx.x] = sh[255];
}

__global__ void scan2_kernel(int* partials, int nchunks) {
    if (threadIdx.x == 0 && blockIdx.x == 0) {
        int run = 0;
        for (int i = 0; i < nchunks; ++i) { int t = partials[i]; partials[i] = run; run += t; }
    }
}

__global__ void scan3_kernel(int* __restrict__ rowp, const int* __restrict__ partials, int n) {
    int i = blockIdx.x * 256 + threadIdx.x;
    if (i < n) rowp[1 + i] += partials[i >> 10];
    if (i == 0) rowp[0] = 0;
}

// W (K x 128, row-major fp32) -> Wt (128 x K, bf16)
__global__ void wtprep_kernel(const float* __restrict__ W, unsigned short* __restrict__ Wt, int K) {
    int idx = blockIdx.x * 256 + threadIdx.x;
    if (idx < 128 * K) {
        int nn = idx / K, k = idx - nn * K;
        Wt[(size_t)nn * K + k] = f2bf(W[(size_t)k * 128 + nn]);
    }
}

// ------------------------------- GEMM --------------------------------------
template <bool A_BF16>
__global__ __launch_bounds__(256)
void gemm_kernel(const void* __restrict__ Aptr, const unsigned short* __restrict__ Wt,
                 unsigned short* __restrict__ Out, int nrows, int K) {
    const int tid  = threadIdx.x;
    const int wave = tid >> 6;
    const int lane = tid & 63;
    const int q = lane >> 4;
    const int r = lane & 15;
    const int wrow = blockIdx.x * 128 + wave * 32;

    f32x4 acc[2][8];
#pragma unroll
    for (int s = 0; s < 2; ++s)
#pragma unroll
        for (int c = 0; c < 8; ++c) acc[s][c] = (f32x4){0.f, 0.f, 0.f, 0.f};

    for (int k0 = 0; k0 < K; k0 += 32) {
        const int kk = k0 + q * 8;
        bf16x8 afrag[2];
#pragma unroll
        for (int s = 0; s < 2; ++s) {
            const int row = wrow + s * 16 + r;
            if (row < nrows) {
                if (A_BF16) {
                    afrag[s] = *reinterpret_cast<const bf16x8*>(
                        reinterpret_cast<const unsigned short*>(Aptr) + (size_t)row * K + kk);
                } else {
                    const float* ap = reinterpret_cast<const float*>(Aptr) + (size_t)row * K + kk;
                    const float4 x0 = *reinterpret_cast<const float4*>(ap);
                    const float4 x1 = *reinterpret_cast<const float4*>(ap + 4);
                    bf16x8 a;
                    a[0] = (__bf16)x0.x; a[1] = (__bf16)x0.y; a[2] = (__bf16)x0.z; a[3] = (__bf16)x0.w;
                    a[4] = (__bf16)x1.x; a[5] = (__bf16)x1.y; a[6] = (__bf16)x1.z; a[7] = (__bf16)x1.w;
                    afrag[s] = a;
                }
            } else {
                bf16x8 a;
#pragma unroll
                for (int j = 0; j < 8; ++j) a[j] = (__bf16)0.f;
                afrag[s] = a;
            }
        }
#pragma unroll
        for (int c = 0; c < 8; ++c) {
            const bf16x8 b = *reinterpret_cast<const bf16x8*>(Wt + (size_t)(c * 16 + r) * K + kk);
#pragma unroll
            for (int s = 0; s < 2; ++s)
                acc[s][c] = __builtin_amdgcn_mfma_f32_16x16x32_bf16(afrag[s], b, acc[s][c], 0, 0, 0);
        }
    }
#pragma unroll
    for (int s = 0; s < 2; ++s)
#pragma unroll
        for (int v = 0; v < 4; ++v) {
            const int row = wrow + s * 16 + q * 4 + v;
            if (row < nrows) {
#pragma unroll
                for (int c = 0; c < 8; ++c)
                    Out[(size_t)row * 128 + c * 16 + r] = f2bf(acc[s][c][v]);
            }
        }
}

// --------------------------- Aggregation -----------------------------------
// One wave per node. Lane l owns features 4c..4c+3 (c=l&31, uint2 = 4 bf16);
// the two 32-lane halves process edges t and t+1 concurrently (dwordx2
// gather = 512B per wave-instruction, half the gather instructions).
// Partial sums merged with shfl_xor(32) BEFORE the nonlinear epilogue.

__global__ __launch_bounds__(256)
void agg1_kernel(const uint2* __restrict__ xw, const uint2* __restrict__ colv2,
                 const int* __restrict__ rowp, const float* __restrict__ dinv,
                 const float* __restrict__ b1, const float* __restrict__ Wc,
                 const float* __restrict__ bc, uint2* __restrict__ h1,
                 float* __restrict__ outp, int n) {
    const int node = blockIdx.x * 4 + (threadIdx.x >> 6);
    if (node >= n) return;
    const int lane = threadIdx.x & 63;
    const int c    = lane & 31;
    const int half = lane >> 5;
    const float di = dinv[node];

    float a0 = 0.f, a1 = 0.f, a2 = 0.f, a3 = 0.f;
    {   // self-loop term (lower half only; merged by the xor-32 reduction)
        const float ws = half ? 0.f : di;
        const uint2 uu = xw[((unsigned)node << 5) + c];
        a0 += bflo(uu.x) * ws;  a1 += bfhi(uu.x) * ws;
        a2 += bflo(uu.y) * ws;  a3 += bfhi(uu.y) * ws;
    }

    const int beg = rowp[node], end = rowp[node + 1];
    for (int base = beg; base < end; base += 64) {
        const int e = base + lane;
        unsigned s = 0; float w = 0.f;
        if (e < end) { uint2 cw = colv2[e]; s = cw.x; w = __uint_as_float(cw.y); }
        const int cnt = min(64, end - base);
#pragma unroll 4
        for (int t = 0; t < cnt; t += 2) {
            const unsigned st = (unsigned)__shfl((int)s, t + half);
            const float    wt = __shfl(w, t + half);
            const uint2 uu = xw[(st << 5) + c];
            a0 += bflo(uu.x) * wt;  a1 += bfhi(uu.x) * wt;
            a2 += bflo(uu.y) * wt;  a3 += bfhi(uu.y) * wt;
        }
    }
    // merge the two halves' partial sums
    a0 += __shfl_xor(a0, 32);  a1 += __shfl_xor(a1, 32);
    a2 += __shfl_xor(a2, 32);  a3 += __shfl_xor(a3, 32);

    const float4 bb = reinterpret_cast<const float4*>(b1)[c];
    a0 = fmaxf(a0 * di + bb.x, 0.f);
    a1 = fmaxf(a1 * di + bb.y, 0.f);
    a2 = fmaxf(a2 * di + bb.z, 0.f);
    a3 = fmaxf(a3 * di + bb.w, 0.f);

    if (half == 0)
        h1[((unsigned)node << 5) + c] = make_uint2(packbf(a0, a1), packbf(a2, a3));

    // logits_coarse: Wc row-major 128x2; feature 4c+j -> Wc[8c+2j], Wc[8c+2j+1]
    const float4 w0 = reinterpret_cast<const float4*>(Wc)[2 * c];      // Wc[8c..8c+3]
    const float4 w1 = reinterpret_cast<const float4*>(Wc)[2 * c + 1];  // Wc[8c+4..8c+7]
    float c0 = a0 * w0.x + a1 * w0.z + a2 * w1.x + a3 * w1.z;
    float c1 = a0 * w0.y + a1 * w0.w + a2 * w1.y + a3 * w1.w;
    if (half) { c0 = 0.f; c1 = 0.f; }   // halves hold duplicates post-merge
#pragma unroll
    for (int off = 32; off; off >>= 1) {
        c0 += __shfl_down(c0, off);
        c1 += __shfl_down(c1, off);
    }
    if (lane == 0) {
        outp[2 * (size_t)node]     = 0.5f * (c0 + bc[0]);
        outp[2 * (size_t)node + 1] = 0.5f * (c1 + bc[1]);
    }
}

__global__ __launch_bounds__(256)
void agg2_kernel(const uint2* __restrict__ xw2, const uint2* __restrict__ h1,
                 const uint2* __restrict__ colv2, const int* __restrict__ rowp,
                 const float* __restrict__ dinv, const float* __restrict__ b2,
                 const float* __restrict__ Wf, const float* __restrict__ bfv,
                 const float* __restrict__ hnode, float* __restrict__ outp, int n) {
    const int node = blockIdx.x * 4 + (threadIdx.x >> 6);
    if (node >= n) return;
    const int lane = threadIdx.x & 63;
    const int c    = lane & 31;
    const int half = lane >> 5;
    const float di = dinv[node];

    float a0 = 0.f, a1 = 0.f, a2 = 0.f, a3 = 0.f;
    {
        const float ws = half ? 0.f : di;
        const uint2 uu = xw2[((unsigned)node << 5) + c];
        a0 += bflo(uu.x) * ws;  a1 += bfhi(uu.x) * ws;
        a2 += bflo(uu.y) * ws;  a3 += bfhi(uu.y) * ws;
    }

    const int beg = rowp[node], end = rowp[node + 1];
    for (int base = beg; base < end; base += 64) {
        const int e = base + lane;
        unsigned s = 0; float w = 0.f;
        if (e < end) { uint2 cw = colv2[e]; s = cw.x; w = __uint_as_float(cw.y); }
        const int cnt = min(64, end - base);
#pragma unroll 4
        for (int t = 0; t < cnt; t += 2) {
            const unsigned st = (unsigned)__shfl((int)s, t + half);
            const float    wt = __shfl(w, t + half);
            const uint2 uu = xw2[(st << 5) + c];
            a0 += bflo(uu.x) * wt;  a1 += bfhi(uu.x) * wt;
            a2 += bflo(uu.y) * wt;  a3 += bfhi(uu.y) * wt;
        }
    }
    a0 += __shfl_xor(a0, 32);  a1 += __shfl_xor(a1, 32);
    a2 += __shfl_xor(a2, 32);  a3 += __shfl_xor(a3, 32);

    const float4 bb = reinterpret_cast<const float4*>(b2)[c];
    float h20 = fmaxf(a0 * di + bb.x, 0.f);
    float h21 = fmaxf(a1 * di + bb.y, 0.f);
    float h22 = fmaxf(a2 * di + bb.z, 0.f);
    float h23 = fmaxf(a3 * di + bb.w, 0.f);

    const float alpha = hnode[node];
    const uint2 hh = h1[((unsigned)node << 5) + c];
    const float ha0 = alpha * h20 + (1.f - alpha) * bflo(hh.x);
    const float ha1 = alpha * h21 + (1.f - alpha) * bfhi(hh.x);
    const float ha2 = alpha * h22 + (1.f - alpha) * bflo(hh.y);
    const float ha3 = alpha * h23 + (1.f - alpha) * bfhi(hh.y);

    const float4 w0 = reinterpret_cast<const float4*>(Wf)[2 * c];
    const float4 w1 = reinterpret_cast<const float4*>(Wf)[2 * c + 1];
    float f0 = ha0 * w0.x + ha1 * w0.z + ha2 * w1.x + ha3 * w1.z;
    float f1 = ha0 * w0.y + ha1 * w0.w + ha2 * w1.y + ha3 * w1.w;
    if (half) { f0 = 0.f; f1 = 0.f; }
#pragma unroll
    for (int off = 32; off; off >>= 1) {
        f0 += __shfl_down(f0, off);
        f1 += __shfl_down(f1, off);
    }
    if (lane == 0) {
        outp[2 * (size_t)node]     += 0.5f * (f0 + bfv[0]);
        outp[2 * (size_t)node + 1] += 0.5f * (f1 + bfv[1]);
    }
}

// ------------------------------ launch -------------------------------------

extern "C" void kernel_launch(void* const* d_in, const int* in_sizes, int n_in,
                              void* d_out, int out_size, void* d_ws, size_t ws_size,
                              hipStream_t stream) {
    const float* x     = (const float*)d_in[0];
    const int*   ei    = (const int*)d_in[1];     // int32 per harness contract
    const float* hnode = (const float*)d_in[2];
    const float* W1    = (const float*)d_in[3];
    const float* b1    = (const float*)d_in[4];
    const float* W2    = (const float*)d_in[5];
    const float* b2    = (const float*)d_in[6];
    const float* Wc    = (const float*)d_in[7];
    const float* bc    = (const float*)d_in[8];
    const float* Wf    = (const float*)d_in[9];
    const float* bfv   = (const float*)d_in[10];

    const int N  = in_sizes[2];
    const int E  = in_sizes[1] / 2;
    const int K1 = in_sizes[3] / HID;   // 256
    const int NB = (N + RANGE - 1) >> SHIFT;
    const int* srcv = ei;
    const int* dstv = ei + E;
    float* outp = (float*)d_out;

    char* ws = (char*)d_ws;
    size_t off = 0;
    auto alloc = [&](size_t bytes) -> char* {
        char* p = ws + off;
        off += (bytes + 255) & ~(size_t)255;
        return p;
    };
    unsigned short* xw       = (unsigned short*)alloc((size_t)N * HID * 2);  // 25.6 MB
    unsigned short* h1       = (unsigned short*)alloc((size_t)N * HID * 2);  // 25.6 MB
    float*          dinv     = (float*)alloc((size_t)N * 4);
    int*            counts   = (int*)alloc((size_t)N * 4);
    int*            rowp     = (int*)alloc((size_t)(N + 1) * 4);
    uint2*          colv2    = (uint2*)alloc((size_t)E * 8);                 // 12.8 MB
    unsigned*       pairs    = (unsigned*)alloc((size_t)E * 4);              // 6.4 MB
    int*            bin_counts = (int*)alloc(MAXB * 4);
    int*            bin_off    = (int*)alloc(MAXB * 4);
    int*            bin_cur    = (int*)alloc(MAXB * 4);
    int*            partials   = (int*)alloc(4096);
    unsigned short* wt1      = (unsigned short*)alloc((size_t)HID * K1 * 2);
    unsigned short* wt2      = (unsigned short*)alloc((size_t)HID * HID * 2);

    hipMemsetAsync(bin_counts, 0, MAXB * 4, stream);
    wtprep_kernel<<<(HID * K1 + 255) / 256, 256, 0, stream>>>(W1, wt1, K1);
    wtprep_kernel<<<(HID * HID + 255) / 256, 256, 0, stream>>>(W2, wt2, HID);

    const int ntiles = (E + TILE - 1) / TILE;
    bincount_kernel<<<ntiles, 256, 0, stream>>>(dstv, bin_counts, E, NB);
    binscan_kernel<<<1, 256, 0, stream>>>(bin_counts, bin_off, bin_cur, NB);
    stage_kernel<<<ntiles, 256, 0, stream>>>(srcv, dstv, bin_cur, pairs, E);
    nodecount_kernel<<<NB, 256, 0, stream>>>(pairs, bin_off, counts, N, NB, E);
    dinv_kernel<<<(N + 255) / 256, 256, 0, stream>>>(counts, dinv, N);

    const int nchunks = (N + 1023) / 1024;
    scan1_kernel<<<nchunks, 256, 0, stream>>>(counts, rowp + 1, partials, N);
    scan2_kernel<<<1, 64, 0, stream>>>(partials, nchunks);
    scan3_kernel<<<(N + 255) / 256, 256, 0, stream>>>(rowp, partials, N);
    fine_kernel<<<NB, 256, 0, stream>>>(pairs, bin_off, rowp, dinv, colv2, N, NB, E);

    gemm_kernel<false><<<(N + 127) / 128, 256, 0, stream>>>((const void*)x, wt1, xw, N, K1);
    agg1_kernel<<<(N + 3) / 4, 256, 0, stream>>>((const uint2*)xw, colv2, rowp, dinv,
                                                 b1, Wc, bc, (uint2*)h1, outp, N);
    gemm_kernel<true><<<(N + 127) / 128, 256, 0, stream>>>((const void*)h1, wt2, xw, N, HID);
    agg2_kernel<<<(N + 3) / 4, 256, 0, stream>>>((const uint2*)xw, (const uint2*)h1, colv2,
                                                 rowp, dinv, b2, Wf, bfv, hnode, outp, N);
}

// Round 6
// 456.352 us; speedup vs baseline: 1.2460x; 1.0753x over previous
//
#include <hip/hip_runtime.h>

// ---------------------------------------------------------------------------
// GCN 2-layer fused pipeline for MI355X (gfx950)
//   h1 = relu(Dinv (A+I) Dinv (x@W1) + b1)
//   out = 0.5*(h1@Wc + bc) + 0.5*((alpha*h2 + (1-alpha)*h1)@Wf + bf)
//   h2 = relu(Dinv (A+I) Dinv (h1@W2) + b2)
// R2: binned counting-sort CSR build (no scattered-atomic writes).
// R3: colv2 = {src, dinv[src]} fused at CSR build.
// R4 FAILED: 8-deep prefetch macro (+VALU, no MLP gain) -> reverted.
// R5 WIN: 2-edge dwordx2 gather, 127->85us. Issue-bound, not byte-bound.
// R6: (a) 4-edge dwordx4 gather (lane owns 8 feats, quarters own edges;
//     ~5.3 instr/edge, vmem instrs halved); (b) CSR chain compaction:
//     nodecount+dinv+scan1/2/3 -> single per-bin binrowp kernel (bin_off is
//     the bin's global edge offset, so only an intra-bin scan is needed).
// ---------------------------------------------------------------------------

#define HID 128
#define SHIFT 9
#define RANGE 512           // nodes per bin = 1<<SHIFT
#define MAXB 256            // max bins (N <= 131072)
#define TILE 4096           // edges per stage block

typedef __bf16 bf16x8 __attribute__((ext_vector_type(8)));
typedef float  f32x4  __attribute__((ext_vector_type(4)));

__device__ __forceinline__ unsigned short f2bf(float x) {
    unsigned int b = __float_as_uint(x);
    b += 0x7fffu + ((b >> 16) & 1u);     // round-to-nearest-even
    return (unsigned short)(b >> 16);
}
__device__ __forceinline__ float bflo(unsigned int u) { return __uint_as_float(u << 16); }
__device__ __forceinline__ float bfhi(unsigned int u) { return __uint_as_float(u & 0xffff0000u); }
__device__ __forceinline__ unsigned packbf(float a, float b) {
    return (unsigned)f2bf(a) | ((unsigned)f2bf(b) << 16);
}

// --------------------------- binned CSR build ------------------------------

__global__ __launch_bounds__(256)
void bincount_kernel(const int* __restrict__ dst, int* __restrict__ bin_counts,
                     int E, int NB) {
    __shared__ int h[MAXB];
    for (int i = threadIdx.x; i < NB; i += 256) h[i] = 0;
    __syncthreads();
    const int base = blockIdx.x * TILE;
#pragma unroll
    for (int j = 0; j < TILE; j += 256) {
        int e = base + j + threadIdx.x;
        if (e < E) atomicAdd(&h[((unsigned)dst[e]) >> SHIFT], 1);
    }
    __syncthreads();
    for (int i = threadIdx.x; i < NB; i += 256) {
        int v = h[i];
        if (v) atomicAdd(&bin_counts[i], v);
    }
}

__global__ void binscan_kernel(const int* __restrict__ bin_counts,
                               int* __restrict__ bin_off, int* __restrict__ bin_cur, int NB) {
    __shared__ int sh[MAXB];
    const int t = threadIdx.x;
    int v = (t < NB) ? bin_counts[t] : 0;
    sh[t] = v;
    __syncthreads();
    for (int s = 1; s < 256; s <<= 1) {
        int x = (t >= s) ? sh[t - s] : 0;
        __syncthreads();
        sh[t] += x;
        __syncthreads();
    }
    if (t < NB) {
        int ex = sh[t] - v;     // exclusive
        bin_off[t] = ex;
        bin_cur[t] = ex;
    }
}

// Block-level binning: tile-local LDS sort by bin, then bin-sorted write-out
// in contiguous runs. pairs[i] = (dlocal<<23) | src   (src < 2^23).
__global__ __launch_bounds__(256)
void stage_kernel(const int* __restrict__ src, const int* __restrict__ dst,
                  int* __restrict__ bin_cur, unsigned* __restrict__ pairs, int E) {
    __shared__ int sh_hist[MAXB];
    __shared__ int sh_off[MAXB];
    __shared__ int sh_ex[MAXB];
    __shared__ int sh_gbase[MAXB];
    __shared__ uint2 stg[TILE];
    const int t = threadIdx.x;
    const int base = blockIdx.x * TILE;
    const int cnt = min(TILE, E - base);

    for (int i = t; i < MAXB; i += 256) sh_hist[i] = 0;
    __syncthreads();

    int s[16], d[16], r[16];
#pragma unroll
    for (int j = 0; j < 16; ++j) {
        const int k = j * 256 + t;
        if (k < cnt) {
            s[j] = src[base + k];
            d[j] = dst[base + k];
            r[j] = atomicAdd(&sh_hist[((unsigned)d[j]) >> SHIFT], 1);
        }
    }
    __syncthreads();

    const int hv = sh_hist[t];
    sh_off[t] = hv;
    __syncthreads();
    for (int st = 1; st < 256; st <<= 1) {
        int x = (t >= st) ? sh_off[t - st] : 0;
        __syncthreads();
        sh_off[t] += x;
        __syncthreads();
    }
    sh_ex[t] = sh_off[t] - hv;                      // exclusive within tile
    if (hv > 0) sh_gbase[t] = atomicAdd(&bin_cur[t], hv);
    __syncthreads();

#pragma unroll
    for (int j = 0; j < 16; ++j) {
        const int k = j * 256 + t;
        if (k < cnt) {
            int b = ((unsigned)d[j]) >> SHIFT;
            stg[sh_ex[b] + r[j]] = make_uint2((unsigned)s[j], (unsigned)d[j]);
        }
    }
    __syncthreads();

    for (int i = t; i < cnt; i += 256) {
        uint2 p = stg[i];
        int b = (int)(p.y >> SHIFT);
        unsigned w = ((p.y & (RANGE - 1)) << 23) | p.x;
        pairs[sh_gbase[b] + (i - sh_ex[b])] = w;
    }
}

// Per-bin: histogram pairs -> counts; intra-bin scan (+bin_off base, which is
// this bin's global edge offset) -> rowp; dinv from counts. Replaces the old
// nodecount + dinv + scan1 + scan2 + scan3 chain.
__global__ __launch_bounds__(256)
void binrowp_kernel(const unsigned* __restrict__ pairs, const int* __restrict__ bin_off,
                    float* __restrict__ dinv, int* __restrict__ rowp,
                    int N, int NB, int E) {
    __shared__ int c[RANGE];
    __shared__ int sh[256];
    const int b = blockIdx.x;
    const int t = threadIdx.x;
    const int nb = b << SHIFT;
    const int nr = min(RANGE, N - nb);
    for (int i = t; i < RANGE; i += 256) c[i] = 0;
    __syncthreads();
    const int lo = bin_off[b];
    const int hi = (b + 1 < NB) ? bin_off[b + 1] : E;
    for (int i = lo + t; i < hi; i += 256)
        atomicAdd(&c[pairs[i] >> 23], 1);
    __syncthreads();
    const int v0 = c[2 * t], v1 = c[2 * t + 1];
    const int pr = v0 + v1;
    sh[t] = pr;
    __syncthreads();
    for (int s = 1; s < 256; s <<= 1) {
        int x = (t >= s) ? sh[t - s] : 0;
        __syncthreads();
        sh[t] += x;
        __syncthreads();
    }
    const int ex = sh[t] - pr + lo;     // exclusive prefix + bin edge base
    if (2 * t < nr) {
        rowp[nb + 2 * t] = ex;
        dinv[nb + 2 * t] = rsqrtf((float)(v0 + 1));
    }
    if (2 * t + 1 < nr) {
        rowp[nb + 2 * t + 1] = ex + v0;
        dinv[nb + 2 * t + 1] = rsqrtf((float)(v1 + 1));
    }
    if (b == 0 && t == 0) rowp[N] = E;
}

// Per-bin fine scatter; emits {src, dinv[src]} so aggs need no dinv gather
__global__ __launch_bounds__(256)
void fine_kernel(const unsigned* __restrict__ pairs, const int* __restrict__ bin_off,
                 const int* __restrict__ rowp, const float* __restrict__ dinv,
                 uint2* __restrict__ colv2, int N, int NB, int E) {
    __shared__ int cur[RANGE];
    const int b = blockIdx.x;
    const int nb = b << SHIFT;
    const int nr = min(RANGE, N - nb);
    for (int i = threadIdx.x; i < nr; i += 256) cur[i] = rowp[nb + i];
    __syncthreads();
    const int lo = bin_off[b];
    const int hi = (b + 1 < NB) ? bin_off[b + 1] : E;
    for (int i = lo + threadIdx.x; i < hi; i += 256) {
        unsigned w = pairs[i];
        unsigned s = w & 0x7fffffu;
        int pos = atomicAdd(&cur[w >> 23], 1);
        colv2[pos] = make_uint2(s, __float_as_uint(dinv[s]));
    }
}

// W (K x 128, row-major fp32) -> Wt (128 x K, bf16)
__global__ void wtprep_kernel(const float* __restrict__ W, unsigned short* __restrict__ Wt, int K) {
    int idx = blockIdx.x * 256 + threadIdx.x;
    if (idx < 128 * K) {
        int nn = idx / K, k = idx - nn * K;
        Wt[(size_t)nn * K + k] = f2bf(W[(size_t)k * 128 + nn]);
    }
}

// ------------------------------- GEMM --------------------------------------
template <bool A_BF16>
__global__ __launch_bounds__(256)
void gemm_kernel(const void* __restrict__ Aptr, const unsigned short* __restrict__ Wt,
                 unsigned short* __restrict__ Out, int nrows, int K) {
    const int tid  = threadIdx.x;
    const int wave = tid >> 6;
    const int lane = tid & 63;
    const int q = lane >> 4;
    const int r = lane & 15;
    const int wrow = blockIdx.x * 128 + wave * 32;

    f32x4 acc[2][8];
#pragma unroll
    for (int s = 0; s < 2; ++s)
#pragma unroll
        for (int c = 0; c < 8; ++c) acc[s][c] = (f32x4){0.f, 0.f, 0.f, 0.f};

    for (int k0 = 0; k0 < K; k0 += 32) {
        const int kk = k0 + q * 8;
        bf16x8 afrag[2];
#pragma unroll
        for (int s = 0; s < 2; ++s) {
            const int row = wrow + s * 16 + r;
            if (row < nrows) {
                if (A_BF16) {
                    afrag[s] = *reinterpret_cast<const bf16x8*>(
                        reinterpret_cast<const unsigned short*>(Aptr) + (size_t)row * K + kk);
                } else {
                    const float* ap = reinterpret_cast<const float*>(Aptr) + (size_t)row * K + kk;
                    const float4 x0 = *reinterpret_cast<const float4*>(ap);
                    const float4 x1 = *reinterpret_cast<const float4*>(ap + 4);
                    bf16x8 a;
                    a[0] = (__bf16)x0.x; a[1] = (__bf16)x0.y; a[2] = (__bf16)x0.z; a[3] = (__bf16)x0.w;
                    a[4] = (__bf16)x1.x; a[5] = (__bf16)x1.y; a[6] = (__bf16)x1.z; a[7] = (__bf16)x1.w;
                    afrag[s] = a;
                }
            } else {
                bf16x8 a;
#pragma unroll
                for (int j = 0; j < 8; ++j) a[j] = (__bf16)0.f;
                afrag[s] = a;
            }
        }
#pragma unroll
        for (int c = 0; c < 8; ++c) {
            const bf16x8 b = *reinterpret_cast<const bf16x8*>(Wt + (size_t)(c * 16 + r) * K + kk);
#pragma unroll
            for (int s = 0; s < 2; ++s)
                acc[s][c] = __builtin_amdgcn_mfma_f32_16x16x32_bf16(afrag[s], b, acc[s][c], 0, 0, 0);
        }
    }
#pragma unroll
    for (int s = 0; s < 2; ++s)
#pragma unroll
        for (int v = 0; v < 4; ++v) {
            const int row = wrow + s * 16 + q * 4 + v;
            if (row < nrows) {
#pragma unroll
                for (int c = 0; c < 8; ++c)
                    Out[(size_t)row * 128 + c * 16 + r] = f2bf(acc[s][c][v]);
            }
        }
}

// --------------------------- Aggregation -----------------------------------
// One wave per node. Lane c=lane&15 owns features 8c..8c+7 (uint4 = 8 bf16);
// the four 16-lane quarters process edges t..t+3 concurrently (dwordx4
// gather = 1KB per wave-instruction). Partial sums merged with
// shfl_xor(16)+shfl_xor(32) BEFORE the nonlinear epilogue.

__global__ __launch_bounds__(256)
void agg1_kernel(const uint4* __restrict__ xw, const uint2* __restrict__ colv2,
                 const int* __restrict__ rowp, const float* __restrict__ dinv,
                 const float* __restrict__ b1, const float* __restrict__ Wc,
                 const float* __restrict__ bc, uint4* __restrict__ h1,
                 float* __restrict__ outp, int n) {
    const int node = blockIdx.x * 4 + (threadIdx.x >> 6);
    if (node >= n) return;
    const int lane = threadIdx.x & 63;
    const int c    = lane & 15;
    const int q4   = lane >> 4;
    const float di = dinv[node];

    float a0=0.f,a1=0.f,a2=0.f,a3=0.f,a4=0.f,a5=0.f,a6=0.f,a7=0.f;
    {   // self-loop (quarter 0 only; merged by xor reductions)
        const float ws = (q4 == 0) ? di : 0.f;
        const uint4 uu = xw[((unsigned)node << 4) + c];
        a0 += bflo(uu.x)*ws; a1 += bfhi(uu.x)*ws;
        a2 += bflo(uu.y)*ws; a3 += bfhi(uu.y)*ws;
        a4 += bflo(uu.z)*ws; a5 += bfhi(uu.z)*ws;
        a6 += bflo(uu.w)*ws; a7 += bfhi(uu.w)*ws;
    }

    const int beg = rowp[node], end = rowp[node + 1];
    for (int base = beg; base < end; base += 64) {
        const int e = base + lane;
        unsigned s = 0; float w = 0.f;
        if (e < end) { uint2 cw = colv2[e]; s = cw.x; w = __uint_as_float(cw.y); }
        const int cnt = min(64, end - base);
#pragma unroll 4
        for (int t = 0; t < cnt; t += 4) {
            const unsigned st = (unsigned)__shfl((int)s, t + q4);
            const float    wt = __shfl(w, t + q4);
            const uint4 uu = xw[(st << 4) + c];
            a0 += bflo(uu.x)*wt; a1 += bfhi(uu.x)*wt;
            a2 += bflo(uu.y)*wt; a3 += bfhi(uu.y)*wt;
            a4 += bflo(uu.z)*wt; a5 += bfhi(uu.z)*wt;
            a6 += bflo(uu.w)*wt; a7 += bfhi(uu.w)*wt;
        }
    }
    // merge the four quarters' partial sums
    a0 += __shfl_xor(a0,16); a1 += __shfl_xor(a1,16);
    a2 += __shfl_xor(a2,16); a3 += __shfl_xor(a3,16);
    a4 += __shfl_xor(a4,16); a5 += __shfl_xor(a5,16);
    a6 += __shfl_xor(a6,16); a7 += __shfl_xor(a7,16);
    a0 += __shfl_xor(a0,32); a1 += __shfl_xor(a1,32);
    a2 += __shfl_xor(a2,32); a3 += __shfl_xor(a3,32);
    a4 += __shfl_xor(a4,32); a5 += __shfl_xor(a5,32);
    a6 += __shfl_xor(a6,32); a7 += __shfl_xor(a7,32);

    const float4 bb0 = reinterpret_cast<const float4*>(b1)[2*c];
    const float4 bb1 = reinterpret_cast<const float4*>(b1)[2*c + 1];
    a0 = fmaxf(a0*di + bb0.x, 0.f);  a1 = fmaxf(a1*di + bb0.y, 0.f);
    a2 = fmaxf(a2*di + bb0.z, 0.f);  a3 = fmaxf(a3*di + bb0.w, 0.f);
    a4 = fmaxf(a4*di + bb1.x, 0.f);  a5 = fmaxf(a5*di + bb1.y, 0.f);
    a6 = fmaxf(a6*di + bb1.z, 0.f);  a7 = fmaxf(a7*di + bb1.w, 0.f);

    if (q4 == 0)
        h1[((unsigned)node << 4) + c] =
            make_uint4(packbf(a0,a1), packbf(a2,a3), packbf(a4,a5), packbf(a6,a7));

    // logits_coarse: Wc row-major 128x2; feature 8c+j -> Wc[16c+2j], Wc[16c+2j+1]
    const float4 w0 = reinterpret_cast<const float4*>(Wc)[4*c];
    const float4 w1 = reinterpret_cast<const float4*>(Wc)[4*c + 1];
    const float4 w2 = reinterpret_cast<const float4*>(Wc)[4*c + 2];
    const float4 w3 = reinterpret_cast<const float4*>(Wc)[4*c + 3];
    float c0 = a0*w0.x + a1*w0.z + a2*w1.x + a3*w1.z
             + a4*w2.x + a5*w2.z + a6*w3.x + a7*w3.z;
    float c1 = a0*w0.y + a1*w0.w + a2*w1.y + a3*w1.w
             + a4*w2.y + a5*w2.w + a6*w3.y + a7*w3.w;
    if (q4) { c0 = 0.f; c1 = 0.f; }   // quarters hold duplicates post-merge
#pragma unroll
    for (int off = 32; off; off >>= 1) {
        c0 += __shfl_down(c0, off);
        c1 += __shfl_down(c1, off);
    }
    if (lane == 0) {
        outp[2 * (size_t)node]     = 0.5f * (c0 + bc[0]);
        outp[2 * (size_t)node + 1] = 0.5f * (c1 + bc[1]);
    }
}

__global__ __launch_bounds__(256)
void agg2_kernel(const uint4* __restrict__ xw2, const uint4* __restrict__ h1,
                 const uint2* __restrict__ colv2, const int* __restrict__ rowp,
                 const float* __restrict__ dinv, const float* __restrict__ b2,
                 const float* __restrict__ Wf, const float* __restrict__ bfv,
                 const float* __restrict__ hnode, float* __restrict__ outp, int n) {
    const int node = blockIdx.x * 4 + (threadIdx.x >> 6);
    if (node >= n) return;
    const int lane = threadIdx.x & 63;
    const int c    = lane & 15;
    const int q4   = lane >> 4;
    const float di = dinv[node];

    float a0=0.f,a1=0.f,a2=0.f,a3=0.f,a4=0.f,a5=0.f,a6=0.f,a7=0.f;
    {
        const float ws = (q4 == 0) ? di : 0.f;
        const uint4 uu = xw2[((unsigned)node << 4) + c];
        a0 += bflo(uu.x)*ws; a1 += bfhi(uu.x)*ws;
        a2 += bflo(uu.y)*ws; a3 += bfhi(uu.y)*ws;
        a4 += bflo(uu.z)*ws; a5 += bfhi(uu.z)*ws;
        a6 += bflo(uu.w)*ws; a7 += bfhi(uu.w)*ws;
    }

    const int beg = rowp[node], end = rowp[node + 1];
    for (int base = beg; base < end; base += 64) {
        const int e = base + lane;
        unsigned s = 0; float w = 0.f;
        if (e < end) { uint2 cw = colv2[e]; s = cw.x; w = __uint_as_float(cw.y); }
        const int cnt = min(64, end - base);
#pragma unroll 4
        for (int t = 0; t < cnt; t += 4) {
            const unsigned st = (unsigned)__shfl((int)s, t + q4);
            const float    wt = __shfl(w, t + q4);
            const uint4 uu = xw2[(st << 4) + c];
            a0 += bflo(uu.x)*wt; a1 += bfhi(uu.x)*wt;
            a2 += bflo(uu.y)*wt; a3 += bfhi(uu.y)*wt;
            a4 += bflo(uu.z)*wt; a5 += bfhi(uu.z)*wt;
            a6 += bflo(uu.w)*wt; a7 += bfhi(uu.w)*wt;
        }
    }
    a0 += __shfl_xor(a0,16); a1 += __shfl_xor(a1,16);
    a2 += __shfl_xor(a2,16); a3 += __shfl_xor(a3,16);
    a4 += __shfl_xor(a4,16); a5 += __shfl_xor(a5,16);
    a6 += __shfl_xor(a6,16); a7 += __shfl_xor(a7,16);
    a0 += __shfl_xor(a0,32); a1 += __shfl_xor(a1,32);
    a2 += __shfl_xor(a2,32); a3 += __shfl_xor(a3,32);
    a4 += __shfl_xor(a4,32); a5 += __shfl_xor(a5,32);
    a6 += __shfl_xor(a6,32); a7 += __shfl_xor(a7,32);

    const float4 bb0 = reinterpret_cast<const float4*>(b2)[2*c];
    const float4 bb1 = reinterpret_cast<const float4*>(b2)[2*c + 1];
    float h20 = fmaxf(a0*di + bb0.x, 0.f);  float h21 = fmaxf(a1*di + bb0.y, 0.f);
    float h22 = fmaxf(a2*di + bb0.z, 0.f);  float h23 = fmaxf(a3*di + bb0.w, 0.f);
    float h24 = fmaxf(a4*di + bb1.x, 0.f);  float h25 = fmaxf(a5*di + bb1.y, 0.f);
    float h26 = fmaxf(a6*di + bb1.z, 0.f);  float h27 = fmaxf(a7*di + bb1.w, 0.f);

    const float alpha = hnode[node];
    const float beta  = 1.f - alpha;
    const uint4 hh = h1[((unsigned)node << 4) + c];
    const float ha0 = alpha*h20 + beta*bflo(hh.x);
    const float ha1 = alpha*h21 + beta*bfhi(hh.x);
    const float ha2 = alpha*h22 + beta*bflo(hh.y);
    const float ha3 = alpha*h23 + beta*bfhi(hh.y);
    const float ha4 = alpha*h24 + beta*bflo(hh.z);
    const float ha5 = alpha*h25 + beta*bfhi(hh.z);
    const float ha6 = alpha*h26 + beta*bflo(hh.w);
    const float ha7 = alpha*h27 + beta*bfhi(hh.w);

    const float4 w0 = reinterpret_cast<const float4*>(Wf)[4*c];
    const float4 w1 = reinterpret_cast<const float4*>(Wf)[4*c + 1];
    const float4 w2 = reinterpret_cast<const float4*>(Wf)[4*c + 2];
    const float4 w3 = reinterpret_cast<const float4*>(Wf)[4*c + 3];
    float f0 = ha0*w0.x + ha1*w0.z + ha2*w1.x + ha3*w1.z
             + ha4*w2.x + ha5*w2.z + ha6*w3.x + ha7*w3.z;
    float f1 = ha0*w0.y + ha1*w0.w + ha2*w1.y + ha3*w1.w
             + ha4*w2.y + ha5*w2.w + ha6*w3.y + ha7*w3.w;
    if (q4) { f0 = 0.f; f1 = 0.f; }
#pragma unroll
    for (int off = 32; off; off >>= 1) {
        f0 += __shfl_down(f0, off);
        f1 += __shfl_down(f1, off);
    }
    if (lane == 0) {
        outp[2 * (size_t)node]     += 0.5f * (f0 + bfv[0]);
        outp[2 * (size_t)node + 1] += 0.5f * (f1 + bfv[1]);
    }
}

// ------------------------------ launch -------------------------------------

extern "C" void kernel_launch(void* const* d_in, const int* in_sizes, int n_in,
                              void* d_out, int out_size, void* d_ws, size_t ws_size,
                              hipStream_t stream) {
    const float* x     = (const float*)d_in[0];
    const int*   ei    = (const int*)d_in[1];     // int32 per harness contract
    const float* hnode = (const float*)d_in[2];
    const float* W1    = (const float*)d_in[3];
    const float* b1    = (const float*)d_in[4];
    const float* W2    = (const float*)d_in[5];
    const float* b2    = (const float*)d_in[6];
    const float* Wc    = (const float*)d_in[7];
    const float* bc    = (const float*)d_in[8];
    const float* Wf    = (const float*)d_in[9];
    const float* bfv   = (const float*)d_in[10];

    const int N  = in_sizes[2];
    const int E  = in_sizes[1] / 2;
    const int K1 = in_sizes[3] / HID;   // 256
    const int NB = (N + RANGE - 1) >> SHIFT;
    const int* srcv = ei;
    const int* dstv = ei + E;
    float* outp = (float*)d_out;

    char* ws = (char*)d_ws;
    size_t off = 0;
    auto alloc = [&](size_t bytes) -> char* {
        char* p = ws + off;
        off += (bytes + 255) & ~(size_t)255;
        return p;
    };
    unsigned short* xw       = (unsigned short*)alloc((size_t)N * HID * 2);  // 25.6 MB
    unsigned short* h1       = (unsigned short*)alloc((size_t)N * HID * 2);  // 25.6 MB
    float*          dinv     = (float*)alloc((size_t)N * 4);
    int*            rowp     = (int*)alloc((size_t)(N + 1) * 4);
    uint2*          colv2    = (uint2*)alloc((size_t)E * 8);                 // 12.8 MB
    unsigned*       pairs    = (unsigned*)alloc((size_t)E * 4);              // 6.4 MB
    int*            bin_counts = (int*)alloc(MAXB * 4);
    int*            bin_off    = (int*)alloc(MAXB * 4);
    int*            bin_cur    = (int*)alloc(MAXB * 4);
    unsigned short* wt1      = (unsigned short*)alloc((size_t)HID * K1 * 2);
    unsigned short* wt2      = (unsigned short*)alloc((size_t)HID * HID * 2);

    hipMemsetAsync(bin_counts, 0, MAXB * 4, stream);
    wtprep_kernel<<<(HID * K1 + 255) / 256, 256, 0, stream>>>(W1, wt1, K1);
    wtprep_kernel<<<(HID * HID + 255) / 256, 256, 0, stream>>>(W2, wt2, HID);

    const int ntiles = (E + TILE - 1) / TILE;
    bincount_kernel<<<ntiles, 256, 0, stream>>>(dstv, bin_counts, E, NB);
    binscan_kernel<<<1, 256, 0, stream>>>(bin_counts, bin_off, bin_cur, NB);
    stage_kernel<<<ntiles, 256, 0, stream>>>(srcv, dstv, bin_cur, pairs, E);
    binrowp_kernel<<<NB, 256, 0, stream>>>(pairs, bin_off, dinv, rowp, N, NB, E);
    fine_kernel<<<NB, 256, 0, stream>>>(pairs, bin_off, rowp, dinv, colv2, N, NB, E);

    gemm_kernel<false><<<(N + 127) / 128, 256, 0, stream>>>((const void*)x, wt1, xw, N, K1);
    agg1_kernel<<<(N + 3) / 4, 256, 0, stream>>>((const uint4*)xw, colv2, rowp, dinv,
                                                 b1, Wc, bc, (uint4*)h1, outp, N);
    gemm_kernel<true><<<(N + 127) / 128, 256, 0, stream>>>((const void*)h1, wt2, xw, N, HID);
    agg2_kernel<<<(N + 3) / 4, 256, 0, stream>>>((const uint4*)xw, (const uint4*)h1, colv2,
                                                 rowp, dinv, b2, Wf, bfv, hnode, outp, N);
}

// Round 7
// 450.442 us; speedup vs baseline: 1.2623x; 1.0131x over previous
//
#include <hip/hip_runtime.h>

// ---------------------------------------------------------------------------
// GCN 2-layer fused pipeline for MI355X (gfx950)
//   h1 = relu(Dinv (A+I) Dinv (x@W1) + b1)
//   out = 0.5*(h1@Wc + bc) + 0.5*((alpha*h2 + (1-alpha)*h1)@Wf + bf)
//   h2 = relu(Dinv (A+I) Dinv (h1@W2) + b2)
// R2: binned counting-sort CSR build. R3: colv2={src,dinv}. R5: 2-edge
// dwordx2 gather. R6: 4-edge dwordx4 gather + one-kernel CSR rowp/dinv.
// R7: gemm was memory-LATENCY bound (MfmaUtil 3%, occupancy 21%, 80us for a
// 16us-floor read): rebuilt as LDS-staged GEMM with async
// global_load_lds(width=16), staging the A-tile in FRAGMENT ORDER so the
// LDS destination is wave-contiguous (HW requirement) and every ds_read_b128
// is stride-1 conflict-free. BK=32, single-buffered, 2 barriers/tile.
// ---------------------------------------------------------------------------

#define HID 128
#define SHIFT 9
#define RANGE 512           // nodes per bin = 1<<SHIFT
#define MAXB 256            // max bins (N <= 131072)
#define TILE 4096           // edges per stage block

typedef __bf16 bf16x8 __attribute__((ext_vector_type(8)));
typedef float  f32x4  __attribute__((ext_vector_type(4)));

__device__ __forceinline__ unsigned short f2bf(float x) {
    unsigned int b = __float_as_uint(x);
    b += 0x7fffu + ((b >> 16) & 1u);     // round-to-nearest-even
    return (unsigned short)(b >> 16);
}
__device__ __forceinline__ float bflo(unsigned int u) { return __uint_as_float(u << 16); }
__device__ __forceinline__ float bfhi(unsigned int u) { return __uint_as_float(u & 0xffff0000u); }
__device__ __forceinline__ unsigned packbf(float a, float b) {
    return (unsigned)f2bf(a) | ((unsigned)f2bf(b) << 16);
}

// async 16B global->LDS (lds dest must be wave-uniform; HW adds lane*16)
__device__ __forceinline__ void gload_lds16(const void* g, void* l) {
    __builtin_amdgcn_global_load_lds(
        (const __attribute__((address_space(1))) void*)g,
        (__attribute__((address_space(3))) void*)l, 16, 0, 0);
}

// --------------------------- binned CSR build ------------------------------

__global__ __launch_bounds__(256)
void bincount_kernel(const int* __restrict__ dst, int* __restrict__ bin_counts,
                     int E, int NB) {
    __shared__ int h[MAXB];
    for (int i = threadIdx.x; i < NB; i += 256) h[i] = 0;
    __syncthreads();
    const int base = blockIdx.x * TILE;
#pragma unroll
    for (int j = 0; j < TILE; j += 256) {
        int e = base + j + threadIdx.x;
        if (e < E) atomicAdd(&h[((unsigned)dst[e]) >> SHIFT], 1);
    }
    __syncthreads();
    for (int i = threadIdx.x; i < NB; i += 256) {
        int v = h[i];
        if (v) atomicAdd(&bin_counts[i], v);
    }
}

__global__ void binscan_kernel(const int* __restrict__ bin_counts,
                               int* __restrict__ bin_off, int* __restrict__ bin_cur, int NB) {
    __shared__ int sh[MAXB];
    const int t = threadIdx.x;
    int v = (t < NB) ? bin_counts[t] : 0;
    sh[t] = v;
    __syncthreads();
    for (int s = 1; s < 256; s <<= 1) {
        int x = (t >= s) ? sh[t - s] : 0;
        __syncthreads();
        sh[t] += x;
        __syncthreads();
    }
    if (t < NB) {
        int ex = sh[t] - v;     // exclusive
        bin_off[t] = ex;
        bin_cur[t] = ex;
    }
}

// Block-level binning: tile-local LDS sort by bin, then bin-sorted write-out
// in contiguous runs. pairs[i] = (dlocal<<23) | src   (src < 2^23).
__global__ __launch_bounds__(256)
void stage_kernel(const int* __restrict__ src, const int* __restrict__ dst,
                  int* __restrict__ bin_cur, unsigned* __restrict__ pairs, int E) {
    __shared__ int sh_hist[MAXB];
    __shared__ int sh_off[MAXB];
    __shared__ int sh_ex[MAXB];
    __shared__ int sh_gbase[MAXB];
    __shared__ uint2 stg[TILE];
    const int t = threadIdx.x;
    const int base = blockIdx.x * TILE;
    const int cnt = min(TILE, E - base);

    for (int i = t; i < MAXB; i += 256) sh_hist[i] = 0;
    __syncthreads();

    int s[16], d[16], r[16];
#pragma unroll
    for (int j = 0; j < 16; ++j) {
        const int k = j * 256 + t;
        if (k < cnt) {
            s[j] = src[base + k];
            d[j] = dst[base + k];
            r[j] = atomicAdd(&sh_hist[((unsigned)d[j]) >> SHIFT], 1);
        }
    }
    __syncthreads();

    const int hv = sh_hist[t];
    sh_off[t] = hv;
    __syncthreads();
    for (int st = 1; st < 256; st <<= 1) {
        int x = (t >= st) ? sh_off[t - st] : 0;
        __syncthreads();
        sh_off[t] += x;
        __syncthreads();
    }
    sh_ex[t] = sh_off[t] - hv;                      // exclusive within tile
    if (hv > 0) sh_gbase[t] = atomicAdd(&bin_cur[t], hv);
    __syncthreads();

#pragma unroll
    for (int j = 0; j < 16; ++j) {
        const int k = j * 256 + t;
        if (k < cnt) {
            int b = ((unsigned)d[j]) >> SHIFT;
            stg[sh_ex[b] + r[j]] = make_uint2((unsigned)s[j], (unsigned)d[j]);
        }
    }
    __syncthreads();

    for (int i = t; i < cnt; i += 256) {
        uint2 p = stg[i];
        int b = (int)(p.y >> SHIFT);
        unsigned w = ((p.y & (RANGE - 1)) << 23) | p.x;
        pairs[sh_gbase[b] + (i - sh_ex[b])] = w;
    }
}

// Per-bin: histogram pairs -> counts; intra-bin scan (+bin_off base) -> rowp;
// dinv from counts.
__global__ __launch_bounds__(256)
void binrowp_kernel(const unsigned* __restrict__ pairs, const int* __restrict__ bin_off,
                    float* __restrict__ dinv, int* __restrict__ rowp,
                    int N, int NB, int E) {
    __shared__ int c[RANGE];
    __shared__ int sh[256];
    const int b = blockIdx.x;
    const int t = threadIdx.x;
    const int nb = b << SHIFT;
    const int nr = min(RANGE, N - nb);
    for (int i = t; i < RANGE; i += 256) c[i] = 0;
    __syncthreads();
    const int lo = bin_off[b];
    const int hi = (b + 1 < NB) ? bin_off[b + 1] : E;
    for (int i = lo + t; i < hi; i += 256)
        atomicAdd(&c[pairs[i] >> 23], 1);
    __syncthreads();
    const int v0 = c[2 * t], v1 = c[2 * t + 1];
    const int pr = v0 + v1;
    sh[t] = pr;
    __syncthreads();
    for (int s = 1; s < 256; s <<= 1) {
        int x = (t >= s) ? sh[t - s] : 0;
        __syncthreads();
        sh[t] += x;
        __syncthreads();
    }
    const int ex = sh[t] - pr + lo;     // exclusive prefix + bin edge base
    if (2 * t < nr) {
        rowp[nb + 2 * t] = ex;
        dinv[nb + 2 * t] = rsqrtf((float)(v0 + 1));
    }
    if (2 * t + 1 < nr) {
        rowp[nb + 2 * t + 1] = ex + v0;
        dinv[nb + 2 * t + 1] = rsqrtf((float)(v1 + 1));
    }
    if (b == 0 && t == 0) rowp[N] = E;
}

// Per-bin fine scatter; emits {src, dinv[src]} so aggs need no dinv gather
__global__ __launch_bounds__(256)
void fine_kernel(const unsigned* __restrict__ pairs, const int* __restrict__ bin_off,
                 const int* __restrict__ rowp, const float* __restrict__ dinv,
                 uint2* __restrict__ colv2, int N, int NB, int E) {
    __shared__ int cur[RANGE];
    const int b = blockIdx.x;
    const int nb = b << SHIFT;
    const int nr = min(RANGE, N - nb);
    for (int i = threadIdx.x; i < nr; i += 256) cur[i] = rowp[nb + i];
    __syncthreads();
    const int lo = bin_off[b];
    const int hi = (b + 1 < NB) ? bin_off[b + 1] : E;
    for (int i = lo + threadIdx.x; i < hi; i += 256) {
        unsigned w = pairs[i];
        unsigned s = w & 0x7fffffu;
        int pos = atomicAdd(&cur[w >> 23], 1);
        colv2[pos] = make_uint2(s, __float_as_uint(dinv[s]));
    }
}

// W (K x 128, row-major fp32) -> Wt (128 x K, bf16)
__global__ void wtprep_kernel(const float* __restrict__ W, unsigned short* __restrict__ Wt, int K) {
    int idx = blockIdx.x * 256 + threadIdx.x;
    if (idx < 128 * K) {
        int nn = idx / K, k = idx - nn * K;
        Wt[(size_t)nn * K + k] = f2bf(W[(size_t)k * 128 + nn]);
    }
}

// ------------------------------- GEMM --------------------------------------
// Out[row][col] (bf16, N x 128) = A (N x K) @ W, via Wt[col][k] bf16.
// Block: 256 thr = 4 waves, 128 rows. A-tile (128 x BK=32) staged to LDS
// with async global_load_lds in FRAGMENT ORDER:
//   16B unit u -> (wave w, s, half, lane l): row = w*32+s*16+(l&15),
//   k = k0 + (l>>4)*8 (+half*4 fp32). LDS dest = contiguous u*16 (HW rule);
//   ds_read_b128 per lane is stride-1, conflict-free.
template <bool A_BF16>
__global__ __launch_bounds__(256)
void gemm_kernel(const void* __restrict__ Aptr, const unsigned short* __restrict__ Wt,
                 unsigned short* __restrict__ Out, int nrows, int K) {
    __shared__ __align__(16) char tilebuf[16384];
    const int tid  = threadIdx.x;
    const int wave = tid >> 6;
    const int lane = tid & 63;
    const int q = lane >> 4;
    const int r = lane & 15;
    const int blkrow = blockIdx.x * 128;
    const int wrow = blkrow + wave * 32;

    f32x4 acc[2][8];
#pragma unroll
    for (int s = 0; s < 2; ++s)
#pragma unroll
        for (int c = 0; c < 8; ++c) acc[s][c] = (f32x4){0.f, 0.f, 0.f, 0.f};

    for (int k0 = 0; k0 < K; k0 += 32) {
        // ---- async stage A-tile (frag order) ----
        if (A_BF16) {
            const unsigned short* A = (const unsigned short*)Aptr;
#pragma unroll
            for (int c = 0; c < 2; ++c) {             // 2 x 4KB
                const int u = tid + c * 256;
                const int l = u & 63;
                const int g = u >> 6;                  // w*2+s
                int row = blkrow + (g >> 1) * 32 + (g & 1) * 16 + (l & 15);
                row = min(row, nrows - 1);
                const int k = k0 + (l >> 4) * 8;
                gload_lds16(A + (size_t)row * K + k,
                            tilebuf + c * 4096 + wave * 1024);
            }
        } else {
            const float* A = (const float*)Aptr;
#pragma unroll
            for (int c = 0; c < 4; ++c) {             // 4 x 4KB
                const int u = tid + c * 256;
                const int l = u & 63;
                const int g = u >> 6;                  // (w*2+s)*2+half
                const int half = g & 1;
                const int ws = g >> 1;
                int row = blkrow + (ws >> 1) * 32 + (ws & 1) * 16 + (l & 15);
                row = min(row, nrows - 1);
                const int k = k0 + (l >> 4) * 8 + half * 4;
                gload_lds16(A + (size_t)row * K + k,
                            tilebuf + c * 4096 + wave * 1024);
            }
        }
        __syncthreads();   // drains vmcnt -> LDS tile valid

        const int kk = k0 + q * 8;
        bf16x8 afrag[2];
#pragma unroll
        for (int s = 0; s < 2; ++s) {
            if (A_BF16) {
                afrag[s] = *reinterpret_cast<const bf16x8*>(
                    tilebuf + ((wave * 2 + s) * 64 + lane) * 16);
            } else {
                const float4 x0 = *reinterpret_cast<const float4*>(
                    tilebuf + (((wave * 2 + s) * 2 + 0) * 64 + lane) * 16);
                const float4 x1 = *reinterpret_cast<const float4*>(
                    tilebuf + (((wave * 2 + s) * 2 + 1) * 64 + lane) * 16);
                bf16x8 a;
                a[0] = (__bf16)x0.x; a[1] = (__bf16)x0.y; a[2] = (__bf16)x0.z; a[3] = (__bf16)x0.w;
                a[4] = (__bf16)x1.x; a[5] = (__bf16)x1.y; a[6] = (__bf16)x1.z; a[7] = (__bf16)x1.w;
                afrag[s] = a;
            }
        }
#pragma unroll
        for (int c = 0; c < 8; ++c) {
            const bf16x8 b = *reinterpret_cast<const bf16x8*>(Wt + (size_t)(c * 16 + r) * K + kk);
#pragma unroll
            for (int s = 0; s < 2; ++s)
                acc[s][c] = __builtin_amdgcn_mfma_f32_16x16x32_bf16(afrag[s], b, acc[s][c], 0, 0, 0);
        }
        __syncthreads();   // tile consumed; safe to overwrite
    }
#pragma unroll
    for (int s = 0; s < 2; ++s)
#pragma unroll
        for (int v = 0; v < 4; ++v) {
            const int row = wrow + s * 16 + q * 4 + v;
            if (row < nrows) {
#pragma unroll
                for (int c = 0; c < 8; ++c)
                    Out[(size_t)row * 128 + c * 16 + r] = f2bf(acc[s][c][v]);
            }
        }
}

// --------------------------- Aggregation -----------------------------------
// One wave per node. Lane c=lane&15 owns features 8c..8c+7 (uint4 = 8 bf16);
// the four 16-lane quarters process edges t..t+3 concurrently (dwordx4
// gather = 1KB per wave-instruction). Partial sums merged with
// shfl_xor(16)+shfl_xor(32) BEFORE the nonlinear epilogue.

__global__ __launch_bounds__(256)
void agg1_kernel(const uint4* __restrict__ xw, const uint2* __restrict__ colv2,
                 const int* __restrict__ rowp, const float* __restrict__ dinv,
                 const float* __restrict__ b1, const float* __restrict__ Wc,
                 const float* __restrict__ bc, uint4* __restrict__ h1,
                 float* __restrict__ outp, int n) {
    const int node = blockIdx.x * 4 + (threadIdx.x >> 6);
    if (node >= n) return;
    const int lane = threadIdx.x & 63;
    const int c    = lane & 15;
    const int q4   = lane >> 4;
    const float di = dinv[node];

    float a0=0.f,a1=0.f,a2=0.f,a3=0.f,a4=0.f,a5=0.f,a6=0.f,a7=0.f;
    {   // self-loop (quarter 0 only; merged by xor reductions)
        const float ws = (q4 == 0) ? di : 0.f;
        const uint4 uu = xw[((unsigned)node << 4) + c];
        a0 += bflo(uu.x)*ws; a1 += bfhi(uu.x)*ws;
        a2 += bflo(uu.y)*ws; a3 += bfhi(uu.y)*ws;
        a4 += bflo(uu.z)*ws; a5 += bfhi(uu.z)*ws;
        a6 += bflo(uu.w)*ws; a7 += bfhi(uu.w)*ws;
    }

    const int beg = rowp[node], end = rowp[node + 1];
    for (int base = beg; base < end; base += 64) {
        const int e = base + lane;
        unsigned s = 0; float w = 0.f;
        if (e < end) { uint2 cw = colv2[e]; s = cw.x; w = __uint_as_float(cw.y); }
        const int cnt = min(64, end - base);
#pragma unroll 4
        for (int t = 0; t < cnt; t += 4) {
            const unsigned st = (unsigned)__shfl((int)s, t + q4);
            const float    wt = __shfl(w, t + q4);
            const uint4 uu = xw[(st << 4) + c];
            a0 += bflo(uu.x)*wt; a1 += bfhi(uu.x)*wt;
            a2 += bflo(uu.y)*wt; a3 += bfhi(uu.y)*wt;
            a4 += bflo(uu.z)*wt; a5 += bfhi(uu.z)*wt;
            a6 += bflo(uu.w)*wt; a7 += bfhi(uu.w)*wt;
        }
    }
    // merge the four quarters' partial sums
    a0 += __shfl_xor(a0,16); a1 += __shfl_xor(a1,16);
    a2 += __shfl_xor(a2,16); a3 += __shfl_xor(a3,16);
    a4 += __shfl_xor(a4,16); a5 += __shfl_xor(a5,16);
    a6 += __shfl_xor(a6,16); a7 += __shfl_xor(a7,16);
    a0 += __shfl_xor(a0,32); a1 += __shfl_xor(a1,32);
    a2 += __shfl_xor(a2,32); a3 += __shfl_xor(a3,32);
    a4 += __shfl_xor(a4,32); a5 += __shfl_xor(a5,32);
    a6 += __shfl_xor(a6,32); a7 += __shfl_xor(a7,32);

    const float4 bb0 = reinterpret_cast<const float4*>(b1)[2*c];
    const float4 bb1 = reinterpret_cast<const float4*>(b1)[2*c + 1];
    a0 = fmaxf(a0*di + bb0.x, 0.f);  a1 = fmaxf(a1*di + bb0.y, 0.f);
    a2 = fmaxf(a2*di + bb0.z, 0.f);  a3 = fmaxf(a3*di + bb0.w, 0.f);
    a4 = fmaxf(a4*di + bb1.x, 0.f);  a5 = fmaxf(a5*di + bb1.y, 0.f);
    a6 = fmaxf(a6*di + bb1.z, 0.f);  a7 = fmaxf(a7*di + bb1.w, 0.f);

    if (q4 == 0)
        h1[((unsigned)node << 4) + c] =
            make_uint4(packbf(a0,a1), packbf(a2,a3), packbf(a4,a5), packbf(a6,a7));

    const float4 w0 = reinterpret_cast<const float4*>(Wc)[4*c];
    const float4 w1 = reinterpret_cast<const float4*>(Wc)[4*c + 1];
    const float4 w2 = reinterpret_cast<const float4*>(Wc)[4*c + 2];
    const float4 w3 = reinterpret_cast<const float4*>(Wc)[4*c + 3];
    float c0 = a0*w0.x + a1*w0.z + a2*w1.x + a3*w1.z
             + a4*w2.x + a5*w2.z + a6*w3.x + a7*w3.z;
    float c1 = a0*w0.y + a1*w0.w + a2*w1.y + a3*w1.w
             + a4*w2.y + a5*w2.w + a6*w3.y + a7*w3.w;
    if (q4) { c0 = 0.f; c1 = 0.f; }   // quarters hold duplicates post-merge
#pragma unroll
    for (int off = 32; off; off >>= 1) {
        c0 += __shfl_down(c0, off);
        c1 += __shfl_down(c1, off);
    }
    if (lane == 0) {
        outp[2 * (size_t)node]     = 0.5f * (c0 + bc[0]);
        outp[2 * (size_t)node + 1] = 0.5f * (c1 + bc[1]);
    }
}

__global__ __launch_bounds__(256)
void agg2_kernel(const uint4* __restrict__ xw2, const uint4* __restrict__ h1,
                 const uint2* __restrict__ colv2, const int* __restrict__ rowp,
                 const float* __restrict__ dinv, const float* __restrict__ b2,
                 const float* __restrict__ Wf, const float* __restrict__ bfv,
                 const float* __restrict__ hnode, float* __restrict__ outp, int n) {
    const int node = blockIdx.x * 4 + (threadIdx.x >> 6);
    if (node >= n) return;
    const int lane = threadIdx.x & 63;
    const int c    = lane & 15;
    const int q4   = lane >> 4;
    const float di = dinv[node];

    float a0=0.f,a1=0.f,a2=0.f,a3=0.f,a4=0.f,a5=0.f,a6=0.f,a7=0.f;
    {
        const float ws = (q4 == 0) ? di : 0.f;
        const uint4 uu = xw2[((unsigned)node << 4) + c];
        a0 += bflo(uu.x)*ws; a1 += bfhi(uu.x)*ws;
        a2 += bflo(uu.y)*ws; a3 += bfhi(uu.y)*ws;
        a4 += bflo(uu.z)*ws; a5 += bfhi(uu.z)*ws;
        a6 += bflo(uu.w)*ws; a7 += bfhi(uu.w)*ws;
    }

    const int beg = rowp[node], end = rowp[node + 1];
    for (int base = beg; base < end; base += 64) {
        const int e = base + lane;
        unsigned s = 0; float w = 0.f;
        if (e < end) { uint2 cw = colv2[e]; s = cw.x; w = __uint_as_float(cw.y); }
        const int cnt = min(64, end - base);
#pragma unroll 4
        for (int t = 0; t < cnt; t += 4) {
            const unsigned st = (unsigned)__shfl((int)s, t + q4);
            const float    wt = __shfl(w, t + q4);
            const uint4 uu = xw2[(st << 4) + c];
            a0 += bflo(uu.x)*wt; a1 += bfhi(uu.x)*wt;
            a2 += bflo(uu.y)*wt; a3 += bfhi(uu.y)*wt;
            a4 += bflo(uu.z)*wt; a5 += bfhi(uu.z)*wt;
            a6 += bflo(uu.w)*wt; a7 += bfhi(uu.w)*wt;
        }
    }
    a0 += __shfl_xor(a0,16); a1 += __shfl_xor(a1,16);
    a2 += __shfl_xor(a2,16); a3 += __shfl_xor(a3,16);
    a4 += __shfl_xor(a4,16); a5 += __shfl_xor(a5,16);
    a6 += __shfl_xor(a6,16); a7 += __shfl_xor(a7,16);
    a0 += __shfl_xor(a0,32); a1 += __shfl_xor(a1,32);
    a2 += __shfl_xor(a2,32); a3 += __shfl_xor(a3,32);
    a4 += __shfl_xor(a4,32); a5 += __shfl_xor(a5,32);
    a6 += __shfl_xor(a6,32); a7 += __shfl_xor(a7,32);

    const float4 bb0 = reinterpret_cast<const float4*>(b2)[2*c];
    const float4 bb1 = reinterpret_cast<const float4*>(b2)[2*c + 1];
    float h20 = fmaxf(a0*di + bb0.x, 0.f);  float h21 = fmaxf(a1*di + bb0.y, 0.f);
    float h22 = fmaxf(a2*di + bb0.z, 0.f);  float h23 = fmaxf(a3*di + bb0.w, 0.f);
    float h24 = fmaxf(a4*di + bb1.x, 0.f);  float h25 = fmaxf(a5*di + bb1.y, 0.f);
    float h26 = fmaxf(a6*di + bb1.z, 0.f);  float h27 = fmaxf(a7*di + bb1.w, 0.f);

    const float alpha = hnode[node];
    const float beta  = 1.f - alpha;
    const uint4 hh = h1[((unsigned)node << 4) + c];
    const float ha0 = alpha*h20 + beta*bflo(hh.x);
    const float ha1 = alpha*h21 + beta*bfhi(hh.x);
    const float ha2 = alpha*h22 + beta*bflo(hh.y);
    const float ha3 = alpha*h23 + beta*bfhi(hh.y);
    const float ha4 = alpha*h24 + beta*bflo(hh.z);
    const float ha5 = alpha*h25 + beta*bfhi(hh.z);
    const float ha6 = alpha*h26 + beta*bflo(hh.w);
    const float ha7 = alpha*h27 + beta*bfhi(hh.w);

    const float4 w0 = reinterpret_cast<const float4*>(Wf)[4*c];
    const float4 w1 = reinterpret_cast<const float4*>(Wf)[4*c + 1];
    const float4 w2 = reinterpret_cast<const float4*>(Wf)[4*c + 2];
    const float4 w3 = reinterpret_cast<const float4*>(Wf)[4*c + 3];
    float f0 = ha0*w0.x + ha1*w0.z + ha2*w1.x + ha3*w1.z
             + ha4*w2.x + ha5*w2.z + ha6*w3.x + ha7*w3.z;
    float f1 = ha0*w0.y + ha1*w0.w + ha2*w1.y + ha3*w1.w
             + ha4*w2.y + ha5*w2.w + ha6*w3.y + ha7*w3.w;
    if (q4) { f0 = 0.f; f1 = 0.f; }
#pragma unroll
    for (int off = 32; off; off >>= 1) {
        f0 += __shfl_down(f0, off);
        f1 += __shfl_down(f1, off);
    }
    if (lane == 0) {
        outp[2 * (size_t)node]     += 0.5f * (f0 + bfv[0]);
        outp[2 * (size_t)node + 1] += 0.5f * (f1 + bfv[1]);
    }
}

// ------------------------------ launch -------------------------------------

extern "C" void kernel_launch(void* const* d_in, const int* in_sizes, int n_in,
                              void* d_out, int out_size, void* d_ws, size_t ws_size,
                              hipStream_t stream) {
    const float* x     = (const float*)d_in[0];
    const int*   ei    = (const int*)d_in[1];     // int32 per harness contract
    const float* hnode = (const float*)d_in[2];
    const float* W1    = (const float*)d_in[3];
    const float* b1    = (const float*)d_in[4];
    const float* W2    = (const float*)d_in[5];
    const float* b2    = (const float*)d_in[6];
    const float* Wc    = (const float*)d_in[7];
    const float* bc    = (const float*)d_in[8];
    const float* Wf    = (const float*)d_in[9];
    const float* bfv   = (const float*)d_in[10];

    const int N  = in_sizes[2];
    const int E  = in_sizes[1] / 2;
    const int K1 = in_sizes[3] / HID;   // 256
    const int NB = (N + RANGE - 1) >> SHIFT;
    const int* srcv = ei;
    const int* dstv = ei + E;
    float* outp = (float*)d_out;

    char* ws = (char*)d_ws;
    size_t off = 0;
    auto alloc = [&](size_t bytes) -> char* {
        char* p = ws + off;
        off += (bytes + 255) & ~(size_t)255;
        return p;
    };
    unsigned short* xw       = (unsigned short*)alloc((size_t)N * HID * 2);  // 25.6 MB
    unsigned short* h1       = (unsigned short*)alloc((size_t)N * HID * 2);  // 25.6 MB
    float*          dinv     = (float*)alloc((size_t)N * 4);
    int*            rowp     = (int*)alloc((size_t)(N + 1) * 4);
    uint2*          colv2    = (uint2*)alloc((size_t)E * 8);                 // 12.8 MB
    unsigned*       pairs    = (unsigned*)alloc((size_t)E * 4);              // 6.4 MB
    int*            bin_counts = (int*)alloc(MAXB * 4);
    int*            bin_off    = (int*)alloc(MAXB * 4);
    int*            bin_cur    = (int*)alloc(MAXB * 4);
    unsigned short* wt1      = (unsigned short*)alloc((size_t)HID * K1 * 2);
    unsigned short* wt2      = (unsigned short*)alloc((size_t)HID * HID * 2);

    hipMemsetAsync(bin_counts, 0, MAXB * 4, stream);
    wtprep_kernel<<<(HID * K1 + 255) / 256, 256, 0, stream>>>(W1, wt1, K1);
    wtprep_kernel<<<(HID * HID + 255) / 256, 256, 0, stream>>>(W2, wt2, HID);

    const int ntiles = (E + TILE - 1) / TILE;
    bincount_kernel<<<ntiles, 256, 0, stream>>>(dstv, bin_counts, E, NB);
    binscan_kernel<<<1, 256, 0, stream>>>(bin_counts, bin_off, bin_cur, NB);
    stage_kernel<<<ntiles, 256, 0, stream>>>(srcv, dstv, bin_cur, pairs, E);
    binrowp_kernel<<<NB, 256, 0, stream>>>(pairs, bin_off, dinv, rowp, N, NB, E);
    fine_kernel<<<NB, 256, 0, stream>>>(pairs, bin_off, rowp, dinv, colv2, N, NB, E);

    gemm_kernel<false><<<(N + 127) / 128, 256, 0, stream>>>((const void*)x, wt1, xw, N, K1);
    agg1_kernel<<<(N + 3) / 4, 256, 0, stream>>>((const uint4*)xw, colv2, rowp, dinv,
                                                 b1, Wc, bc, (uint4*)h1, outp, N);
    gemm_kernel<true><<<(N + 127) / 128, 256, 0, stream>>>((const void*)h1, wt2, xw, N, HID);
    agg2_kernel<<<(N + 3) / 4, 256, 0, stream>>>((const uint4*)xw, (const uint4*)h1, colv2,
                                                 rowp, dinv, b2, Wf, bfv, hnode, outp, N);
}

// Round 8
// 445.684 us; speedup vs baseline: 1.2758x; 1.0107x over previous
//
#include <hip/hip_runtime.h>

// ---------------------------------------------------------------------------
// GCN 2-layer fused pipeline for MI355X (gfx950)
//   h1 = relu(Dinv (A+I) Dinv (x@W1) + b1)
//   out = 0.5*(h1@Wc + bc) + 0.5*((alpha*h2 + (1-alpha)*h1)@Wf + bf)
//   h2 = relu(Dinv (A+I) Dinv (h1@W2) + b2)
// R2: binned counting-sort CSR. R3: fused dinv into colv. R5/R6: multi-edge
// wide gathers (dwordx2/x4). R7: LDS-staged GEMM via global_load_lds(16).
// R8: (a) colv packed to ONE dword: (st<<15)|fixed15(dinv[src]) -> halves
//     colv bytes, ONE shuffle per 4-edge group (was 2, on the dep chain);
//     (b) f32x2 accumulators to coax v_pk_fma_f32 (VOP3P, 2 FLOP/instr);
//     (c) 32-bit gather offsets (st<<8)+(c<<4); (d) wtprep x2 + memset
//     merged into one prep_kernel.
// ---------------------------------------------------------------------------

#define HID 128
#define SHIFT 9
#define RANGE 512           // nodes per bin = 1<<SHIFT
#define MAXB 256            // max bins (N <= 131072)
#define TILE 4096           // edges per stage block

typedef __bf16 bf16x8 __attribute__((ext_vector_type(8)));
typedef float  f32x4  __attribute__((ext_vector_type(4)));
typedef float  f32x2  __attribute__((ext_vector_type(2)));

__device__ __forceinline__ unsigned short f2bf(float x) {
    unsigned int b = __float_as_uint(x);
    b += 0x7fffu + ((b >> 16) & 1u);     // round-to-nearest-even
    return (unsigned short)(b >> 16);
}
__device__ __forceinline__ float bflo(unsigned int u) { return __uint_as_float(u << 16); }
__device__ __forceinline__ float bfhi(unsigned int u) { return __uint_as_float(u & 0xffff0000u); }
__device__ __forceinline__ unsigned packbf(float a, float b) {
    return (unsigned)f2bf(a) | ((unsigned)f2bf(b) << 16);
}

// async 16B global->LDS (lds dest must be wave-uniform; HW adds lane*16)
__device__ __forceinline__ void gload_lds16(const void* g, void* l) {
    __builtin_amdgcn_global_load_lds(
        (const __attribute__((address_space(1))) void*)g,
        (__attribute__((address_space(3))) void*)l, 16, 0, 0);
}

// --------------------------- binned CSR build ------------------------------

__global__ __launch_bounds__(256)
void bincount_kernel(const int* __restrict__ dst, int* __restrict__ bin_counts,
                     int E, int NB) {
    __shared__ int h[MAXB];
    for (int i = threadIdx.x; i < NB; i += 256) h[i] = 0;
    __syncthreads();
    const int base = blockIdx.x * TILE;
#pragma unroll
    for (int j = 0; j < TILE; j += 256) {
        int e = base + j + threadIdx.x;
        if (e < E) atomicAdd(&h[((unsigned)dst[e]) >> SHIFT], 1);
    }
    __syncthreads();
    for (int i = threadIdx.x; i < NB; i += 256) {
        int v = h[i];
        if (v) atomicAdd(&bin_counts[i], v);
    }
}

__global__ void binscan_kernel(const int* __restrict__ bin_counts,
                               int* __restrict__ bin_off, int* __restrict__ bin_cur, int NB) {
    __shared__ int sh[MAXB];
    const int t = threadIdx.x;
    int v = (t < NB) ? bin_counts[t] : 0;
    sh[t] = v;
    __syncthreads();
    for (int s = 1; s < 256; s <<= 1) {
        int x = (t >= s) ? sh[t - s] : 0;
        __syncthreads();
        sh[t] += x;
        __syncthreads();
    }
    if (t < NB) {
        int ex = sh[t] - v;     // exclusive
        bin_off[t] = ex;
        bin_cur[t] = ex;
    }
}

// Block-level binning: tile-local LDS sort by bin, then bin-sorted write-out
// in contiguous runs. pairs[i] = (dlocal<<23) | src   (src < 2^23).
__global__ __launch_bounds__(256)
void stage_kernel(const int* __restrict__ src, const int* __restrict__ dst,
                  int* __restrict__ bin_cur, unsigned* __restrict__ pairs, int E) {
    __shared__ int sh_hist[MAXB];
    __shared__ int sh_off[MAXB];
    __shared__ int sh_ex[MAXB];
    __shared__ int sh_gbase[MAXB];
    __shared__ uint2 stg[TILE];
    const int t = threadIdx.x;
    const int base = blockIdx.x * TILE;
    const int cnt = min(TILE, E - base);

    for (int i = t; i < MAXB; i += 256) sh_hist[i] = 0;
    __syncthreads();

    int s[16], d[16], r[16];
#pragma unroll
    for (int j = 0; j < 16; ++j) {
        const int k = j * 256 + t;
        if (k < cnt) {
            s[j] = src[base + k];
            d[j] = dst[base + k];
            r[j] = atomicAdd(&sh_hist[((unsigned)d[j]) >> SHIFT], 1);
        }
    }
    __syncthreads();

    const int hv = sh_hist[t];
    sh_off[t] = hv;
    __syncthreads();
    for (int st = 1; st < 256; st <<= 1) {
        int x = (t >= st) ? sh_off[t - st] : 0;
        __syncthreads();
        sh_off[t] += x;
        __syncthreads();
    }
    sh_ex[t] = sh_off[t] - hv;                      // exclusive within tile
    if (hv > 0) sh_gbase[t] = atomicAdd(&bin_cur[t], hv);
    __syncthreads();

#pragma unroll
    for (int j = 0; j < 16; ++j) {
        const int k = j * 256 + t;
        if (k < cnt) {
            int b = ((unsigned)d[j]) >> SHIFT;
            stg[sh_ex[b] + r[j]] = make_uint2((unsigned)s[j], (unsigned)d[j]);
        }
    }
    __syncthreads();

    for (int i = t; i < cnt; i += 256) {
        uint2 p = stg[i];
        int b = (int)(p.y >> SHIFT);
        unsigned w = ((p.y & (RANGE - 1)) << 23) | p.x;
        pairs[sh_gbase[b] + (i - sh_ex[b])] = w;
    }
}

// Per-bin: histogram pairs -> counts; intra-bin scan (+bin_off base) -> rowp;
// dinv from counts.
__global__ __launch_bounds__(256)
void binrowp_kernel(const unsigned* __restrict__ pairs, const int* __restrict__ bin_off,
                    float* __restrict__ dinv, int* __restrict__ rowp,
                    int N, int NB, int E) {
    __shared__ int c[RANGE];
    __shared__ int sh[256];
    const int b = blockIdx.x;
    const int t = threadIdx.x;
    const int nb = b << SHIFT;
    const int nr = min(RANGE, N - nb);
    for (int i = t; i < RANGE; i += 256) c[i] = 0;
    __syncthreads();
    const int lo = bin_off[b];
    const int hi = (b + 1 < NB) ? bin_off[b + 1] : E;
    for (int i = lo + t; i < hi; i += 256)
        atomicAdd(&c[pairs[i] >> 23], 1);
    __syncthreads();
    const int v0 = c[2 * t], v1 = c[2 * t + 1];
    const int pr = v0 + v1;
    sh[t] = pr;
    __syncthreads();
    for (int s = 1; s < 256; s <<= 1) {
        int x = (t >= s) ? sh[t - s] : 0;
        __syncthreads();
        sh[t] += x;
        __syncthreads();
    }
    const int ex = sh[t] - pr + lo;     // exclusive prefix + bin edge base
    if (2 * t < nr) {
        rowp[nb + 2 * t] = ex;
        dinv[nb + 2 * t] = rsqrtf((float)(v0 + 1));
    }
    if (2 * t + 1 < nr) {
        rowp[nb + 2 * t + 1] = ex + v0;
        dinv[nb + 2 * t + 1] = rsqrtf((float)(v1 + 1));
    }
    if (b == 0 && t == 0) rowp[N] = E;
}

// Per-bin fine scatter; emits packed (src<<15)|fixed15(dinv[src]) so the agg
// hot loop needs ONE dword + ONE shuffle per edge-group.
__global__ __launch_bounds__(256)
void fine_kernel(const unsigned* __restrict__ pairs, const int* __restrict__ bin_off,
                 const int* __restrict__ rowp, const float* __restrict__ dinv,
                 unsigned* __restrict__ colv1, int N, int NB, int E) {
    __shared__ int cur[RANGE];
    const int b = blockIdx.x;
    const int nb = b << SHIFT;
    const int nr = min(RANGE, N - nb);
    for (int i = threadIdx.x; i < nr; i += 256) cur[i] = rowp[nb + i];
    __syncthreads();
    const int lo = bin_off[b];
    const int hi = (b + 1 < NB) ? bin_off[b + 1] : E;
    for (int i = lo + threadIdx.x; i < hi; i += 256) {
        unsigned w = pairs[i];
        unsigned s = w & 0x7fffffu;
        int pos = atomicAdd(&cur[w >> 23], 1);
        unsigned w15 = __float2uint_rn(dinv[s] * 32767.0f);   // dinv in (0,1]
        colv1[pos] = (s << 15) | w15;
    }
}

// Merged prep: zero bin_counts + both weight transposes (Wt[col][k] bf16)
__global__ void prep_kernel(const float* __restrict__ W1, const float* __restrict__ W2,
                            unsigned short* __restrict__ wt1, unsigned short* __restrict__ wt2,
                            int K1, int* __restrict__ bin_counts) {
    int idx = blockIdx.x * 256 + threadIdx.x;
    if (idx < MAXB) bin_counts[idx] = 0;
    if (idx < 128 * K1) {
        int nn = idx / K1, k = idx - nn * K1;
        wt1[(size_t)nn * K1 + k] = f2bf(W1[(size_t)k * 128 + nn]);
    }
    if (idx < 128 * 128) {
        int nn = idx >> 7, k = idx & 127;
        wt2[(size_t)nn * 128 + k] = f2bf(W2[(size_t)k * 128 + nn]);
    }
}

// ------------------------------- GEMM --------------------------------------
// Out[row][col] (bf16, N x 128) = A (N x K) @ W, via Wt[col][k] bf16.
// A-tile (128 x BK=32) staged to LDS async in FRAGMENT ORDER (see R7 note).
template <bool A_BF16>
__global__ __launch_bounds__(256)
void gemm_kernel(const void* __restrict__ Aptr, const unsigned short* __restrict__ Wt,
                 unsigned short* __restrict__ Out, int nrows, int K) {
    __shared__ __align__(16) char tilebuf[16384];
    const int tid  = threadIdx.x;
    const int wave = tid >> 6;
    const int lane = tid & 63;
    const int q = lane >> 4;
    const int r = lane & 15;
    const int blkrow = blockIdx.x * 128;
    const int wrow = blkrow + wave * 32;

    f32x4 acc[2][8];
#pragma unroll
    for (int s = 0; s < 2; ++s)
#pragma unroll
        for (int c = 0; c < 8; ++c) acc[s][c] = (f32x4){0.f, 0.f, 0.f, 0.f};

    for (int k0 = 0; k0 < K; k0 += 32) {
        if (A_BF16) {
            const unsigned short* A = (const unsigned short*)Aptr;
#pragma unroll
            for (int c = 0; c < 2; ++c) {             // 2 x 4KB
                const int u = tid + c * 256;
                const int l = u & 63;
                const int g = u >> 6;
                int row = blkrow + (g >> 1) * 32 + (g & 1) * 16 + (l & 15);
                row = min(row, nrows - 1);
                const int k = k0 + (l >> 4) * 8;
                gload_lds16(A + (size_t)row * K + k,
                            tilebuf + c * 4096 + wave * 1024);
            }
        } else {
            const float* A = (const float*)Aptr;
#pragma unroll
            for (int c = 0; c < 4; ++c) {             // 4 x 4KB
                const int u = tid + c * 256;
                const int l = u & 63;
                const int g = u >> 6;
                const int half = g & 1;
                const int ws = g >> 1;
                int row = blkrow + (ws >> 1) * 32 + (ws & 1) * 16 + (l & 15);
                row = min(row, nrows - 1);
                const int k = k0 + (l >> 4) * 8 + half * 4;
                gload_lds16(A + (size_t)row * K + k,
                            tilebuf + c * 4096 + wave * 1024);
            }
        }
        __syncthreads();

        const int kk = k0 + q * 8;
        bf16x8 afrag[2];
#pragma unroll
        for (int s = 0; s < 2; ++s) {
            if (A_BF16) {
                afrag[s] = *reinterpret_cast<const bf16x8*>(
                    tilebuf + ((wave * 2 + s) * 64 + lane) * 16);
            } else {
                const float4 x0 = *reinterpret_cast<const float4*>(
                    tilebuf + (((wave * 2 + s) * 2 + 0) * 64 + lane) * 16);
                const float4 x1 = *reinterpret_cast<const float4*>(
                    tilebuf + (((wave * 2 + s) * 2 + 1) * 64 + lane) * 16);
                bf16x8 a;
                a[0] = (__bf16)x0.x; a[1] = (__bf16)x0.y; a[2] = (__bf16)x0.z; a[3] = (__bf16)x0.w;
                a[4] = (__bf16)x1.x; a[5] = (__bf16)x1.y; a[6] = (__bf16)x1.z; a[7] = (__bf16)x1.w;
                afrag[s] = a;
            }
        }
#pragma unroll
        for (int c = 0; c < 8; ++c) {
            const bf16x8 b = *reinterpret_cast<const bf16x8*>(Wt + (size_t)(c * 16 + r) * K + kk);
#pragma unroll
            for (int s = 0; s < 2; ++s)
                acc[s][c] = __builtin_amdgcn_mfma_f32_16x16x32_bf16(afrag[s], b, acc[s][c], 0, 0, 0);
        }
        __syncthreads();
    }
#pragma unroll
    for (int s = 0; s < 2; ++s)
#pragma unroll
        for (int v = 0; v < 4; ++v) {
            const int row = wrow + s * 16 + q * 4 + v;
            if (row < nrows) {
#pragma unroll
                for (int c = 0; c < 8; ++c)
                    Out[(size_t)row * 128 + c * 16 + r] = f2bf(acc[s][c][v]);
            }
        }
}

// --------------------------- Aggregation -----------------------------------
// One wave per node. Lane c=lane&15 owns features 8c..8c+7 (uint4 = 8 bf16);
// four 16-lane quarters process edges t..t+3 concurrently (dwordx4 gather =
// 1KB/wave-instr). colv entry packed (st<<15)|w15 -> ONE shuffle per group.
// f32x2 accumulators target v_pk_fma_f32. Merge via shfl_xor(16,32).

#define AGG_EDGE_LOOP(XW)                                                      \
    for (int base = beg; base < end; base += 64) {                             \
        const int e = base + lane;                                             \
        const unsigned cw = (e < end) ? colv1[e] : 0u;                         \
        const int cnt = min(64, end - base);                                   \
        _Pragma("unroll 4")                                                    \
        for (int t = 0; t < cnt; t += 4) {                                     \
            const unsigned cg = (unsigned)__shfl((int)cw, t + q4);             \
            const unsigned st = cg >> 15;                                      \
            const float    wt = (float)(cg & 0x7fffu) * (1.0f / 32767.0f);     \
            const uint4 uu = *reinterpret_cast<const uint4*>(                  \
                (const char*)(XW) + ((st << 8) + coff));                       \
            A0 += (f32x2){bflo(uu.x), bfhi(uu.x)} * wt;                        \
            A1 += (f32x2){bflo(uu.y), bfhi(uu.y)} * wt;                        \
            A2 += (f32x2){bflo(uu.z), bfhi(uu.z)} * wt;                        \
            A3 += (f32x2){bflo(uu.w), bfhi(uu.w)} * wt;                        \
        }                                                                      \
    }                                                                          \
    A0 += __shfl_xor(A0, 16); A1 += __shfl_xor(A1, 16);                        \
    A2 += __shfl_xor(A2, 16); A3 += __shfl_xor(A3, 16);                        \
    A0 += __shfl_xor(A0, 32); A1 += __shfl_xor(A1, 32);                        \
    A2 += __shfl_xor(A2, 32); A3 += __shfl_xor(A3, 32);

__device__ __forceinline__ f32x2 __shfl_xor(f32x2 v, int m) {
    return (f32x2){__shfl_xor(v[0], m), __shfl_xor(v[1], m)};
}

__global__ __launch_bounds__(256)
void agg1_kernel(const unsigned short* __restrict__ xw, const unsigned* __restrict__ colv1,
                 const int* __restrict__ rowp, const float* __restrict__ dinv,
                 const float* __restrict__ b1, const float* __restrict__ Wc,
                 const float* __restrict__ bc, uint4* __restrict__ h1,
                 float* __restrict__ outp, int n) {
    const int node = blockIdx.x * 4 + (threadIdx.x >> 6);
    if (node >= n) return;
    const int lane = threadIdx.x & 63;
    const int c    = lane & 15;
    const int q4   = lane >> 4;
    const unsigned coff = (unsigned)c << 4;
    const float di = dinv[node];

    f32x2 A0 = {0.f,0.f}, A1 = {0.f,0.f}, A2 = {0.f,0.f}, A3 = {0.f,0.f};
    {   // self-loop (quarter 0 only; merged by xor reductions)
        const float ws = (q4 == 0) ? di : 0.f;
        const uint4 uu = *reinterpret_cast<const uint4*>(
            (const char*)xw + (((unsigned)node << 8) + coff));
        A0 += (f32x2){bflo(uu.x), bfhi(uu.x)} * ws;
        A1 += (f32x2){bflo(uu.y), bfhi(uu.y)} * ws;
        A2 += (f32x2){bflo(uu.z), bfhi(uu.z)} * ws;
        A3 += (f32x2){bflo(uu.w), bfhi(uu.w)} * ws;
    }

    const int beg = rowp[node], end = rowp[node + 1];
    AGG_EDGE_LOOP(xw)

    const float4 bb0 = reinterpret_cast<const float4*>(b1)[2*c];
    const float4 bb1 = reinterpret_cast<const float4*>(b1)[2*c + 1];
    float a0 = fmaxf(A0[0]*di + bb0.x, 0.f), a1 = fmaxf(A0[1]*di + bb0.y, 0.f);
    float a2 = fmaxf(A1[0]*di + bb0.z, 0.f), a3 = fmaxf(A1[1]*di + bb0.w, 0.f);
    float a4 = fmaxf(A2[0]*di + bb1.x, 0.f), a5 = fmaxf(A2[1]*di + bb1.y, 0.f);
    float a6 = fmaxf(A3[0]*di + bb1.z, 0.f), a7 = fmaxf(A3[1]*di + bb1.w, 0.f);

    if (q4 == 0)
        h1[((unsigned)node << 4) + c] =
            make_uint4(packbf(a0,a1), packbf(a2,a3), packbf(a4,a5), packbf(a6,a7));

    const float4 w0 = reinterpret_cast<const float4*>(Wc)[4*c];
    const float4 w1 = reinterpret_cast<const float4*>(Wc)[4*c + 1];
    const float4 w2 = reinterpret_cast<const float4*>(Wc)[4*c + 2];
    const float4 w3 = reinterpret_cast<const float4*>(Wc)[4*c + 3];
    float c0 = a0*w0.x + a1*w0.z + a2*w1.x + a3*w1.z
             + a4*w2.x + a5*w2.z + a6*w3.x + a7*w3.z;
    float c1 = a0*w0.y + a1*w0.w + a2*w1.y + a3*w1.w
             + a4*w2.y + a5*w2.w + a6*w3.y + a7*w3.w;
    if (q4) { c0 = 0.f; c1 = 0.f; }   // quarters hold duplicates post-merge
#pragma unroll
    for (int off = 32; off; off >>= 1) {
        c0 += __shfl_down(c0, off);
        c1 += __shfl_down(c1, off);
    }
    if (lane == 0) {
        outp[2 * (size_t)node]     = 0.5f * (c0 + bc[0]);
        outp[2 * (size_t)node + 1] = 0.5f * (c1 + bc[1]);
    }
}

__global__ __launch_bounds__(256)
void agg2_kernel(const unsigned short* __restrict__ xw2, const uint4* __restrict__ h1,
                 const unsigned* __restrict__ colv1, const int* __restrict__ rowp,
                 const float* __restrict__ dinv, const float* __restrict__ b2,
                 const float* __restrict__ Wf, const float* __restrict__ bfv,
                 const float* __restrict__ hnode, float* __restrict__ outp, int n) {
    const int node = blockIdx.x * 4 + (threadIdx.x >> 6);
    if (node >= n) return;
    const int lane = threadIdx.x & 63;
    const int c    = lane & 15;
    const int q4   = lane >> 4;
    const unsigned coff = (unsigned)c << 4;
    const float di = dinv[node];

    f32x2 A0 = {0.f,0.f}, A1 = {0.f,0.f}, A2 = {0.f,0.f}, A3 = {0.f,0.f};
    {
        const float ws = (q4 == 0) ? di : 0.f;
        const uint4 uu = *reinterpret_cast<const uint4*>(
            (const char*)xw2 + (((unsigned)node << 8) + coff));
        A0 += (f32x2){bflo(uu.x), bfhi(uu.x)} * ws;
        A1 += (f32x2){bflo(uu.y), bfhi(uu.y)} * ws;
        A2 += (f32x2){bflo(uu.z), bfhi(uu.z)} * ws;
        A3 += (f32x2){bflo(uu.w), bfhi(uu.w)} * ws;
    }

    const int beg = rowp[node], end = rowp[node + 1];
    AGG_EDGE_LOOP(xw2)

    const float4 bb0 = reinterpret_cast<const float4*>(b2)[2*c];
    const float4 bb1 = reinterpret_cast<const float4*>(b2)[2*c + 1];
    float h20 = fmaxf(A0[0]*di + bb0.x, 0.f), h21 = fmaxf(A0[1]*di + bb0.y, 0.f);
    float h22 = fmaxf(A1[0]*di + bb0.z, 0.f), h23 = fmaxf(A1[1]*di + bb0.w, 0.f);
    float h24 = fmaxf(A2[0]*di + bb1.x, 0.f), h25 = fmaxf(A2[1]*di + bb1.y, 0.f);
    float h26 = fmaxf(A3[0]*di + bb1.z, 0.f), h27 = fmaxf(A3[1]*di + bb1.w, 0.f);

    const float alpha = hnode[node];
    const float beta  = 1.f - alpha;
    const uint4 hh = h1[((unsigned)node << 4) + c];
    const float ha0 = alpha*h20 + beta*bflo(hh.x);
    const float ha1 = alpha*h21 + beta*bfhi(hh.x);
    const float ha2 = alpha*h22 + beta*bflo(hh.y);
    const float ha3 = alpha*h23 + beta*bfhi(hh.y);
    const float ha4 = alpha*h24 + beta*bflo(hh.z);
    const float ha5 = alpha*h25 + beta*bfhi(hh.z);
    const float ha6 = alpha*h26 + beta*bflo(hh.w);
    const float ha7 = alpha*h27 + beta*bfhi(hh.w);

    const float4 w0 = reinterpret_cast<const float4*>(Wf)[4*c];
    const float4 w1 = reinterpret_cast<const float4*>(Wf)[4*c + 1];
    const float4 w2 = reinterpret_cast<const float4*>(Wf)[4*c + 2];
    const float4 w3 = reinterpret_cast<const float4*>(Wf)[4*c + 3];
    float f0 = ha0*w0.x + ha1*w0.z + ha2*w1.x + ha3*w1.z
             + ha4*w2.x + ha5*w2.z + ha6*w3.x + ha7*w3.z;
    float f1 = ha0*w0.y + ha1*w0.w + ha2*w1.y + ha3*w1.w
             + ha4*w2.y + ha5*w2.w + ha6*w3.y + ha7*w3.w;
    if (q4) { f0 = 0.f; f1 = 0.f; }
#pragma unroll
    for (int off = 32; off; off >>= 1) {
        f0 += __shfl_down(f0, off);
        f1 += __shfl_down(f1, off);
    }
    if (lane == 0) {
        outp[2 * (size_t)node]     += 0.5f * (f0 + bfv[0]);
        outp[2 * (size_t)node + 1] += 0.5f * (f1 + bfv[1]);
    }
}

// ------------------------------ launch -------------------------------------

extern "C" void kernel_launch(void* const* d_in, const int* in_sizes, int n_in,
                              void* d_out, int out_size, void* d_ws, size_t ws_size,
                              hipStream_t stream) {
    const float* x     = (const float*)d_in[0];
    const int*   ei    = (const int*)d_in[1];     // int32 per harness contract
    const float* hnode = (const float*)d_in[2];
    const float* W1    = (const float*)d_in[3];
    const float* b1    = (const float*)d_in[4];
    const float* W2    = (const float*)d_in[5];
    const float* b2    = (const float*)d_in[6];
    const float* Wc    = (const float*)d_in[7];
    const float* bc    = (const float*)d_in[8];
    const float* Wf    = (const float*)d_in[9];
    const float* bfv   = (const float*)d_in[10];

    const int N  = in_sizes[2];
    const int E  = in_sizes[1] / 2;
    const int K1 = in_sizes[3] / HID;   // 256
    const int NB = (N + RANGE - 1) >> SHIFT;
    const int* srcv = ei;
    const int* dstv = ei + E;
    float* outp = (float*)d_out;

    char* ws = (char*)d_ws;
    size_t off = 0;
    auto alloc = [&](size_t bytes) -> char* {
        char* p = ws + off;
        off += (bytes + 255) & ~(size_t)255;
        return p;
    };
    unsigned short* xw       = (unsigned short*)alloc((size_t)N * HID * 2);  // 25.6 MB
    unsigned short* h1       = (unsigned short*)alloc((size_t)N * HID * 2);  // 25.6 MB
    float*          dinv     = (float*)alloc((size_t)N * 4);
    int*            rowp     = (int*)alloc((size_t)(N + 1) * 4);
    unsigned*       colv1    = (unsigned*)alloc((size_t)E * 4);              // 6.4 MB
    unsigned*       pairs    = (unsigned*)alloc((size_t)E * 4);              // 6.4 MB
    int*            bin_counts = (int*)alloc(MAXB * 4);
    int*            bin_off    = (int*)alloc(MAXB * 4);
    int*            bin_cur    = (int*)alloc(MAXB * 4);
    unsigned short* wt1      = (unsigned short*)alloc((size_t)HID * K1 * 2);
    unsigned short* wt2      = (unsigned short*)alloc((size_t)HID * HID * 2);

    prep_kernel<<<(HID * K1 + 255) / 256, 256, 0, stream>>>(W1, W2, wt1, wt2, K1, bin_counts);

    const int ntiles = (E + TILE - 1) / TILE;
    bincount_kernel<<<ntiles, 256, 0, stream>>>(dstv, bin_counts, E, NB);
    binscan_kernel<<<1, 256, 0, stream>>>(bin_counts, bin_off, bin_cur, NB);
    stage_kernel<<<ntiles, 256, 0, stream>>>(srcv, dstv, bin_cur, pairs, E);
    binrowp_kernel<<<NB, 256, 0, stream>>>(pairs, bin_off, dinv, rowp, N, NB, E);
    fine_kernel<<<NB, 256, 0, stream>>>(pairs, bin_off, rowp, dinv, colv1, N, NB, E);

    gemm_kernel<false><<<(N + 127) / 128, 256, 0, stream>>>((const void*)x, wt1, xw, N, K1);
    agg1_kernel<<<(N + 3) / 4, 256, 0, stream>>>(xw, colv1, rowp, dinv,
                                                 b1, Wc, bc, (uint4*)h1, outp, N);
    gemm_kernel<true><<<(N + 127) / 128, 256, 0, stream>>>((const void*)h1, wt2, xw, N, HID);
    agg2_kernel<<<(N + 3) / 4, 256, 0, stream>>>(xw, (const uint4*)h1, colv1,
                                                 rowp, dinv, b2, Wf, bfv, hnode, outp, N);
}

// Round 9
// 432.752 us; speedup vs baseline: 1.3139x; 1.0299x over previous
//
#include <hip/hip_runtime.h>

// ---------------------------------------------------------------------------
// GCN 2-layer fused pipeline for MI355X (gfx950)
//   h1 = relu(Dinv (A+I) Dinv (x@W1) + b1)
//   out = 0.5*(h1@Wc + bc) + 0.5*((alpha*h2 + (1-alpha)*h1)@Wf + bf)
//   h2 = relu(Dinv (A+I) Dinv (h1@W2) + b2)
// R2: binned counting-sort CSR. R3: fused dinv into colv. R5/R6: multi-edge
// wide gathers. R8: 1-dword colv (st<<15|w15), packed f32x2 agg math.
// R7 FAILED for gemm (LDS+barrier K-loop stays latency-bound at low
// occupancy: MfmaUtil 3%, 78us vs 16us HBM floor).
// R9: barrier-free register-pipelined GEMM. Each wave owns 32 rows, K is a
// template constant, A-loads run in a DEPTH=4 software pipe (16KB/wave in
// flight > Little's-law need), B loaded per-iteration (L2-hit), MFMA waits
// only on B while A refills stay outstanding. No LDS, no __syncthreads.
// ---------------------------------------------------------------------------

#define HID 128
#define SHIFT 9
#define RANGE 512           // nodes per bin = 1<<SHIFT
#define MAXB 256            // max bins (N <= 131072)
#define TILE 4096           // edges per stage block

typedef __bf16 bf16x8 __attribute__((ext_vector_type(8)));
typedef float  f32x4  __attribute__((ext_vector_type(4)));
typedef float  f32x2  __attribute__((ext_vector_type(2)));

__device__ __forceinline__ unsigned short f2bf(float x) {
    unsigned int b = __float_as_uint(x);
    b += 0x7fffu + ((b >> 16) & 1u);     // round-to-nearest-even
    return (unsigned short)(b >> 16);
}
__device__ __forceinline__ float bflo(unsigned int u) { return __uint_as_float(u << 16); }
__device__ __forceinline__ float bfhi(unsigned int u) { return __uint_as_float(u & 0xffff0000u); }
__device__ __forceinline__ unsigned packbf(float a, float b) {
    return (unsigned)f2bf(a) | ((unsigned)f2bf(b) << 16);
}

// --------------------------- binned CSR build ------------------------------

__global__ __launch_bounds__(256)
void bincount_kernel(const int* __restrict__ dst, int* __restrict__ bin_counts,
                     int E, int NB) {
    __shared__ int h[MAXB];
    for (int i = threadIdx.x; i < NB; i += 256) h[i] = 0;
    __syncthreads();
    const int base = blockIdx.x * TILE;
#pragma unroll
    for (int j = 0; j < TILE; j += 256) {
        int e = base + j + threadIdx.x;
        if (e < E) atomicAdd(&h[((unsigned)dst[e]) >> SHIFT], 1);
    }
    __syncthreads();
    for (int i = threadIdx.x; i < NB; i += 256) {
        int v = h[i];
        if (v) atomicAdd(&bin_counts[i], v);
    }
}

__global__ void binscan_kernel(const int* __restrict__ bin_counts,
                               int* __restrict__ bin_off, int* __restrict__ bin_cur, int NB) {
    __shared__ int sh[MAXB];
    const int t = threadIdx.x;
    int v = (t < NB) ? bin_counts[t] : 0;
    sh[t] = v;
    __syncthreads();
    for (int s = 1; s < 256; s <<= 1) {
        int x = (t >= s) ? sh[t - s] : 0;
        __syncthreads();
        sh[t] += x;
        __syncthreads();
    }
    if (t < NB) {
        int ex = sh[t] - v;     // exclusive
        bin_off[t] = ex;
        bin_cur[t] = ex;
    }
}

// Block-level binning: tile-local LDS sort by bin, then bin-sorted write-out
// in contiguous runs. pairs[i] = (dlocal<<23) | src   (src < 2^23).
__global__ __launch_bounds__(256)
void stage_kernel(const int* __restrict__ src, const int* __restrict__ dst,
                  int* __restrict__ bin_cur, unsigned* __restrict__ pairs, int E) {
    __shared__ int sh_hist[MAXB];
    __shared__ int sh_off[MAXB];
    __shared__ int sh_ex[MAXB];
    __shared__ int sh_gbase[MAXB];
    __shared__ uint2 stg[TILE];
    const int t = threadIdx.x;
    const int base = blockIdx.x * TILE;
    const int cnt = min(TILE, E - base);

    for (int i = t; i < MAXB; i += 256) sh_hist[i] = 0;
    __syncthreads();

    int s[16], d[16], r[16];
#pragma unroll
    for (int j = 0; j < 16; ++j) {
        const int k = j * 256 + t;
        if (k < cnt) {
            s[j] = src[base + k];
            d[j] = dst[base + k];
            r[j] = atomicAdd(&sh_hist[((unsigned)d[j]) >> SHIFT], 1);
        }
    }
    __syncthreads();

    const int hv = sh_hist[t];
    sh_off[t] = hv;
    __syncthreads();
    for (int st = 1; st < 256; st <<= 1) {
        int x = (t >= st) ? sh_off[t - st] : 0;
        __syncthreads();
        sh_off[t] += x;
        __syncthreads();
    }
    sh_ex[t] = sh_off[t] - hv;                      // exclusive within tile
    if (hv > 0) sh_gbase[t] = atomicAdd(&bin_cur[t], hv);
    __syncthreads();

#pragma unroll
    for (int j = 0; j < 16; ++j) {
        const int k = j * 256 + t;
        if (k < cnt) {
            int b = ((unsigned)d[j]) >> SHIFT;
            stg[sh_ex[b] + r[j]] = make_uint2((unsigned)s[j], (unsigned)d[j]);
        }
    }
    __syncthreads();

    for (int i = t; i < cnt; i += 256) {
        uint2 p = stg[i];
        int b = (int)(p.y >> SHIFT);
        unsigned w = ((p.y & (RANGE - 1)) << 23) | p.x;
        pairs[sh_gbase[b] + (i - sh_ex[b])] = w;
    }
}

// Per-bin: histogram pairs -> counts; intra-bin scan (+bin_off base) -> rowp;
// dinv from counts.
__global__ __launch_bounds__(256)
void binrowp_kernel(const unsigned* __restrict__ pairs, const int* __restrict__ bin_off,
                    float* __restrict__ dinv, int* __restrict__ rowp,
                    int N, int NB, int E) {
    __shared__ int c[RANGE];
    __shared__ int sh[256];
    const int b = blockIdx.x;
    const int t = threadIdx.x;
    const int nb = b << SHIFT;
    const int nr = min(RANGE, N - nb);
    for (int i = t; i < RANGE; i += 256) c[i] = 0;
    __syncthreads();
    const int lo = bin_off[b];
    const int hi = (b + 1 < NB) ? bin_off[b + 1] : E;
    for (int i = lo + t; i < hi; i += 256)
        atomicAdd(&c[pairs[i] >> 23], 1);
    __syncthreads();
    const int v0 = c[2 * t], v1 = c[2 * t + 1];
    const int pr = v0 + v1;
    sh[t] = pr;
    __syncthreads();
    for (int s = 1; s < 256; s <<= 1) {
        int x = (t >= s) ? sh[t - s] : 0;
        __syncthreads();
        sh[t] += x;
        __syncthreads();
    }
    const int ex = sh[t] - pr + lo;     // exclusive prefix + bin edge base
    if (2 * t < nr) {
        rowp[nb + 2 * t] = ex;
        dinv[nb + 2 * t] = rsqrtf((float)(v0 + 1));
    }
    if (2 * t + 1 < nr) {
        rowp[nb + 2 * t + 1] = ex + v0;
        dinv[nb + 2 * t + 1] = rsqrtf((float)(v1 + 1));
    }
    if (b == 0 && t == 0) rowp[N] = E;
}

// Per-bin fine scatter; emits packed (src<<15)|fixed15(dinv[src])
__global__ __launch_bounds__(256)
void fine_kernel(const unsigned* __restrict__ pairs, const int* __restrict__ bin_off,
                 const int* __restrict__ rowp, const float* __restrict__ dinv,
                 unsigned* __restrict__ colv1, int N, int NB, int E) {
    __shared__ int cur[RANGE];
    const int b = blockIdx.x;
    const int nb = b << SHIFT;
    const int nr = min(RANGE, N - nb);
    for (int i = threadIdx.x; i < nr; i += 256) cur[i] = rowp[nb + i];
    __syncthreads();
    const int lo = bin_off[b];
    const int hi = (b + 1 < NB) ? bin_off[b + 1] : E;
    for (int i = lo + threadIdx.x; i < hi; i += 256) {
        unsigned w = pairs[i];
        unsigned s = w & 0x7fffffu;
        int pos = atomicAdd(&cur[w >> 23], 1);
        unsigned w15 = __float2uint_rn(dinv[s] * 32767.0f);   // dinv in (0,1]
        colv1[pos] = (s << 15) | w15;
    }
}

// Merged prep: zero bin_counts + both weight transposes (Wt[col][k] bf16)
__global__ void prep_kernel(const float* __restrict__ W1, const float* __restrict__ W2,
                            unsigned short* __restrict__ wt1, unsigned short* __restrict__ wt2,
                            int K1, int* __restrict__ bin_counts) {
    int idx = blockIdx.x * 256 + threadIdx.x;
    if (idx < MAXB) bin_counts[idx] = 0;
    if (idx < 128 * K1) {
        int nn = idx / K1, k = idx - nn * K1;
        wt1[(size_t)nn * K1 + k] = f2bf(W1[(size_t)k * 128 + nn]);
    }
    if (idx < 128 * 128) {
        int nn = idx >> 7, k = idx & 127;
        wt2[(size_t)nn * 128 + k] = f2bf(W2[(size_t)k * 128 + nn]);
    }
}

// ------------------------------- GEMM --------------------------------------
// Out[row][col] (bf16, N x 128) = A (N x K) @ W, via Wt[col][k] bf16.
// Barrier-free, LDS-free. Each wave = independent 32 rows (2x16 MFMA tiles).
// A-loads software-pipelined DEPTH=4 K-steps deep (full unroll, K constexpr);
// per iteration: B loads -> consume oldest A -> refill A slot -> MFMA (waits
// only on B; A refills stay in flight).
template <bool A_BF16, int K>
__global__ __launch_bounds__(256)
void gemm_kernel(const void* __restrict__ Aptr, const unsigned short* __restrict__ Wt,
                 unsigned short* __restrict__ Out, int nrows) {
    constexpr int NIT = K / 32;
    constexpr int DEPTH = (NIT < 4) ? NIT : 4;
    const int tid  = threadIdx.x;
    const int wave = tid >> 6;
    const int lane = tid & 63;
    const int q = lane >> 4;
    const int r = lane & 15;
    const int wrow = blockIdx.x * 128 + wave * 32;
    const size_t row0 = (size_t)min(wrow + r,      nrows - 1);
    const size_t row1 = (size_t)min(wrow + 16 + r, nrows - 1);

    const unsigned short* A16 = (const unsigned short*)Aptr;
    const float*          A32 = (const float*)Aptr;

    f32x4 acc[2][8];
#pragma unroll
    for (int s = 0; s < 2; ++s)
#pragma unroll
        for (int c = 0; c < 8; ++c) acc[s][c] = (f32x4){0.f, 0.f, 0.f, 0.f};

    bf16x8 preb[DEPTH][2];
    float4 pref[DEPTH][2][2];

    // prologue: fill the A pipe
#pragma unroll
    for (int i = 0; i < DEPTH; ++i) {
        const int kk = i * 32 + q * 8;
        if (A_BF16) {
            preb[i][0] = *reinterpret_cast<const bf16x8*>(A16 + row0 * K + kk);
            preb[i][1] = *reinterpret_cast<const bf16x8*>(A16 + row1 * K + kk);
        } else {
            pref[i][0][0] = *reinterpret_cast<const float4*>(A32 + row0 * K + kk);
            pref[i][0][1] = *reinterpret_cast<const float4*>(A32 + row0 * K + kk + 4);
            pref[i][1][0] = *reinterpret_cast<const float4*>(A32 + row1 * K + kk);
            pref[i][1][1] = *reinterpret_cast<const float4*>(A32 + row1 * K + kk + 4);
        }
    }

#pragma unroll
    for (int it = 0; it < NIT; ++it) {
        const int slot = it % DEPTH;
        const int kk = it * 32 + q * 8;

        // B fragments for this K-step (L1/L2-resident after first blocks)
        bf16x8 bfr[8];
#pragma unroll
        for (int c = 0; c < 8; ++c)
            bfr[c] = *reinterpret_cast<const bf16x8*>(Wt + (size_t)(c * 16 + r) * K + kk);

        // consume oldest A slot into afrag (waitcnt covers only these loads)
        bf16x8 afrag[2];
#pragma unroll
        for (int s = 0; s < 2; ++s) {
            if (A_BF16) {
                afrag[s] = preb[slot][s];
            } else {
                const float4 x0 = pref[slot][s][0];
                const float4 x1 = pref[slot][s][1];
                bf16x8 a;
                a[0] = (__bf16)x0.x; a[1] = (__bf16)x0.y; a[2] = (__bf16)x0.z; a[3] = (__bf16)x0.w;
                a[4] = (__bf16)x1.x; a[5] = (__bf16)x1.y; a[6] = (__bf16)x1.z; a[7] = (__bf16)x1.w;
                afrag[s] = a;
            }
        }

        // refill the pipe slot (issued after B, so MFMA's B-wait skips these)
        if (it + DEPTH < NIT) {
            const int kk2 = (it + DEPTH) * 32 + q * 8;
            if (A_BF16) {
                preb[slot][0] = *reinterpret_cast<const bf16x8*>(A16 + row0 * K + kk2);
                preb[slot][1] = *reinterpret_cast<const bf16x8*>(A16 + row1 * K + kk2);
            } else {
                pref[slot][0][0] = *reinterpret_cast<const float4*>(A32 + row0 * K + kk2);
                pref[slot][0][1] = *reinterpret_cast<const float4*>(A32 + row0 * K + kk2 + 4);
                pref[slot][1][0] = *reinterpret_cast<const float4*>(A32 + row1 * K + kk2);
                pref[slot][1][1] = *reinterpret_cast<const float4*>(A32 + row1 * K + kk2 + 4);
            }
        }

#pragma unroll
        for (int c = 0; c < 8; ++c) {
            acc[0][c] = __builtin_amdgcn_mfma_f32_16x16x32_bf16(afrag[0], bfr[c], acc[0][c], 0, 0, 0);
            acc[1][c] = __builtin_amdgcn_mfma_f32_16x16x32_bf16(afrag[1], bfr[c], acc[1][c], 0, 0, 0);
        }
    }

#pragma unroll
    for (int s = 0; s < 2; ++s)
#pragma unroll
        for (int v = 0; v < 4; ++v) {
            const int row = wrow + s * 16 + q * 4 + v;
            if (row < nrows) {
#pragma unroll
                for (int c = 0; c < 8; ++c)
                    Out[(size_t)row * 128 + c * 16 + r] = f2bf(acc[s][c][v]);
            }
        }
}

// --------------------------- Aggregation -----------------------------------
// One wave per node. Lane c=lane&15 owns features 8c..8c+7 (uint4 = 8 bf16);
// four 16-lane quarters process edges t..t+3 concurrently (dwordx4 gather =
// 1KB/wave-instr). colv entry packed (st<<15)|w15 -> ONE shuffle per group.
// f32x2 accumulators target v_pk_fma_f32. Merge via shfl_xor(16,32).

#define AGG_EDGE_LOOP(XW)                                                      \
    for (int base = beg; base < end; base += 64) {                             \
        const int e = base + lane;                                             \
        const unsigned cw = (e < end) ? colv1[e] : 0u;                         \
        const int cnt = min(64, end - base);                                   \
        _Pragma("unroll 4")                                                    \
        for (int t = 0; t < cnt; t += 4) {                                     \
            const unsigned cg = (unsigned)__shfl((int)cw, t + q4);             \
            const unsigned st = cg >> 15;                                      \
            const float    wt = (float)(cg & 0x7fffu) * (1.0f / 32767.0f);     \
            const uint4 uu = *reinterpret_cast<const uint4*>(                  \
                (const char*)(XW) + ((st << 8) + coff));                       \
            A0 += (f32x2){bflo(uu.x), bfhi(uu.x)} * wt;                        \
            A1 += (f32x2){bflo(uu.y), bfhi(uu.y)} * wt;                        \
            A2 += (f32x2){bflo(uu.z), bfhi(uu.z)} * wt;                        \
            A3 += (f32x2){bflo(uu.w), bfhi(uu.w)} * wt;                        \
        }                                                                      \
    }                                                                          \
    A0 += __shfl_xor(A0, 16); A1 += __shfl_xor(A1, 16);                        \
    A2 += __shfl_xor(A2, 16); A3 += __shfl_xor(A3, 16);                        \
    A0 += __shfl_xor(A0, 32); A1 += __shfl_xor(A1, 32);                        \
    A2 += __shfl_xor(A2, 32); A3 += __shfl_xor(A3, 32);

__device__ __forceinline__ f32x2 __shfl_xor(f32x2 v, int m) {
    return (f32x2){__shfl_xor(v[0], m), __shfl_xor(v[1], m)};
}

__global__ __launch_bounds__(256)
void agg1_kernel(const unsigned short* __restrict__ xw, const unsigned* __restrict__ colv1,
                 const int* __restrict__ rowp, const float* __restrict__ dinv,
                 const float* __restrict__ b1, const float* __restrict__ Wc,
                 const float* __restrict__ bc, uint4* __restrict__ h1,
                 float* __restrict__ outp, int n) {
    const int node = blockIdx.x * 4 + (threadIdx.x >> 6);
    if (node >= n) return;
    const int lane = threadIdx.x & 63;
    const int c    = lane & 15;
    const int q4   = lane >> 4;
    const unsigned coff = (unsigned)c << 4;
    const float di = dinv[node];

    f32x2 A0 = {0.f,0.f}, A1 = {0.f,0.f}, A2 = {0.f,0.f}, A3 = {0.f,0.f};
    {   // self-loop (quarter 0 only; merged by xor reductions)
        const float ws = (q4 == 0) ? di : 0.f;
        const uint4 uu = *reinterpret_cast<const uint4*>(
            (const char*)xw + (((unsigned)node << 8) + coff));
        A0 += (f32x2){bflo(uu.x), bfhi(uu.x)} * ws;
        A1 += (f32x2){bflo(uu.y), bfhi(uu.y)} * ws;
        A2 += (f32x2){bflo(uu.z), bfhi(uu.z)} * ws;
        A3 += (f32x2){bflo(uu.w), bfhi(uu.w)} * ws;
    }

    const int beg = rowp[node], end = rowp[node + 1];
    AGG_EDGE_LOOP(xw)

    const float4 bb0 = reinterpret_cast<const float4*>(b1)[2*c];
    const float4 bb1 = reinterpret_cast<const float4*>(b1)[2*c + 1];
    float a0 = fmaxf(A0[0]*di + bb0.x, 0.f), a1 = fmaxf(A0[1]*di + bb0.y, 0.f);
    float a2 = fmaxf(A1[0]*di + bb0.z, 0.f), a3 = fmaxf(A1[1]*di + bb0.w, 0.f);
    float a4 = fmaxf(A2[0]*di + bb1.x, 0.f), a5 = fmaxf(A2[1]*di + bb1.y, 0.f);
    float a6 = fmaxf(A3[0]*di + bb1.z, 0.f), a7 = fmaxf(A3[1]*di + bb1.w, 0.f);

    if (q4 == 0)
        h1[((unsigned)node << 4) + c] =
            make_uint4(packbf(a0,a1), packbf(a2,a3), packbf(a4,a5), packbf(a6,a7));

    const float4 w0 = reinterpret_cast<const float4*>(Wc)[4*c];
    const float4 w1 = reinterpret_cast<const float4*>(Wc)[4*c + 1];
    const float4 w2 = reinterpret_cast<const float4*>(Wc)[4*c + 2];
    const float4 w3 = reinterpret_cast<const float4*>(Wc)[4*c + 3];
    float c0 = a0*w0.x + a1*w0.z + a2*w1.x + a3*w1.z
             + a4*w2.x + a5*w2.z + a6*w3.x + a7*w3.z;
    float c1 = a0*w0.y + a1*w0.w + a2*w1.y + a3*w1.w
             + a4*w2.y + a5*w2.w + a6*w3.y + a7*w3.w;
    if (q4) { c0 = 0.f; c1 = 0.f; }   // quarters hold duplicates post-merge
#pragma unroll
    for (int off = 32; off; off >>= 1) {
        c0 += __shfl_down(c0, off);
        c1 += __shfl_down(c1, off);
    }
    if (lane == 0) {
        outp[2 * (size_t)node]     = 0.5f * (c0 + bc[0]);
        outp[2 * (size_t)node + 1] = 0.5f * (c1 + bc[1]);
    }
}

__global__ __launch_bounds__(256)
void agg2_kernel(const unsigned short* __restrict__ xw2, const uint4* __restrict__ h1,
                 const unsigned* __restrict__ colv1, const int* __restrict__ rowp,
                 const float* __restrict__ dinv, const float* __restrict__ b2,
                 const float* __restrict__ Wf, const float* __restrict__ bfv,
                 const float* __restrict__ hnode, float* __restrict__ outp, int n) {
    const int node = blockIdx.x * 4 + (threadIdx.x >> 6);
    if (node >= n) return;
    const int lane = threadIdx.x & 63;
    const int c    = lane & 15;
    const int q4   = lane >> 4;
    const unsigned coff = (unsigned)c << 4;
    const float di = dinv[node];

    f32x2 A0 = {0.f,0.f}, A1 = {0.f,0.f}, A2 = {0.f,0.f}, A3 = {0.f,0.f};
    {
        const float ws = (q4 == 0) ? di : 0.f;
        const uint4 uu = *reinterpret_cast<const uint4*>(
            (const char*)xw2 + (((unsigned)node << 8) + coff));
        A0 += (f32x2){bflo(uu.x), bfhi(uu.x)} * ws;
        A1 += (f32x2){bflo(uu.y), bfhi(uu.y)} * ws;
        A2 += (f32x2){bflo(uu.z), bfhi(uu.z)} * ws;
        A3 += (f32x2){bflo(uu.w), bfhi(uu.w)} * ws;
    }

    const int beg = rowp[node], end = rowp[node + 1];
    AGG_EDGE_LOOP(xw2)

    const float4 bb0 = reinterpret_cast<const float4*>(b2)[2*c];
    const float4 bb1 = reinterpret_cast<const float4*>(b2)[2*c + 1];
    float h20 = fmaxf(A0[0]*di + bb0.x, 0.f), h21 = fmaxf(A0[1]*di + bb0.y, 0.f);
    float h22 = fmaxf(A1[0]*di + bb0.z, 0.f), h23 = fmaxf(A1[1]*di + bb0.w, 0.f);
    float h24 = fmaxf(A2[0]*di + bb1.x, 0.f), h25 = fmaxf(A2[1]*di + bb1.y, 0.f);
    float h26 = fmaxf(A3[0]*di + bb1.z, 0.f), h27 = fmaxf(A3[1]*di + bb1.w, 0.f);

    const float alpha = hnode[node];
    const float beta  = 1.f - alpha;
    const uint4 hh = h1[((unsigned)node << 4) + c];
    const float ha0 = alpha*h20 + beta*bflo(hh.x);
    const float ha1 = alpha*h21 + beta*bfhi(hh.x);
    const float ha2 = alpha*h22 + beta*bflo(hh.y);
    const float ha3 = alpha*h23 + beta*bfhi(hh.y);
    const float ha4 = alpha*h24 + beta*bflo(hh.z);
    const float ha5 = alpha*h25 + beta*bfhi(hh.z);
    const float ha6 = alpha*h26 + beta*bflo(hh.w);
    const float ha7 = alpha*h27 + beta*bfhi(hh.w);

    const float4 w0 = reinterpret_cast<const float4*>(Wf)[4*c];
    const float4 w1 = reinterpret_cast<const float4*>(Wf)[4*c + 1];
    const float4 w2 = reinterpret_cast<const float4*>(Wf)[4*c + 2];
    const float4 w3 = reinterpret_cast<const float4*>(Wf)[4*c + 3];
    float f0 = ha0*w0.x + ha1*w0.z + ha2*w1.x + ha3*w1.z
             + ha4*w2.x + ha5*w2.z + ha6*w3.x + ha7*w3.z;
    float f1 = ha0*w0.y + ha1*w0.w + ha2*w1.y + ha3*w1.w
             + ha4*w2.y + ha5*w2.w + ha6*w3.y + ha7*w3.w;
    if (q4) { f0 = 0.f; f1 = 0.f; }
#pragma unroll
    for (int off = 32; off; off >>= 1) {
        f0 += __shfl_down(f0, off);
        f1 += __shfl_down(f1, off);
    }
    if (lane == 0) {
        outp[2 * (size_t)node]     += 0.5f * (f0 + bfv[0]);
        outp[2 * (size_t)node + 1] += 0.5f * (f1 + bfv[1]);
    }
}

// ------------------------------ launch -------------------------------------

extern "C" void kernel_launch(void* const* d_in, const int* in_sizes, int n_in,
                              void* d_out, int out_size, void* d_ws, size_t ws_size,
                              hipStream_t stream) {
    const float* x     = (const float*)d_in[0];
    const int*   ei    = (const int*)d_in[1];     // int32 per harness contract
    const float* hnode = (const float*)d_in[2];
    const float* W1    = (const float*)d_in[3];
    const float* b1    = (const float*)d_in[4];
    const float* W2    = (const float*)d_in[5];
    const float* b2    = (const float*)d_in[6];
    const float* Wc    = (const float*)d_in[7];
    const float* bc    = (const float*)d_in[8];
    const float* Wf    = (const float*)d_in[9];
    const float* bfv   = (const float*)d_in[10];

    const int N  = in_sizes[2];
    const int E  = in_sizes[1] / 2;
    const int K1 = in_sizes[3] / HID;   // 256 (fixed by problem shape)
    const int NB = (N + RANGE - 1) >> SHIFT;
    const int* srcv = ei;
    const int* dstv = ei + E;
    float* outp = (float*)d_out;

    char* ws = (char*)d_ws;
    size_t off = 0;
    auto alloc = [&](size_t bytes) -> char* {
        char* p = ws + off;
        off += (bytes + 255) & ~(size_t)255;
        return p;
    };
    unsigned short* xw       = (unsigned short*)alloc((size_t)N * HID * 2);  // 25.6 MB
    unsigned short* h1       = (unsigned short*)alloc((size_t)N * HID * 2);  // 25.6 MB
    float*          dinv     = (float*)alloc((size_t)N * 4);
    int*            rowp     = (int*)alloc((size_t)(N + 1) * 4);
    unsigned*       colv1    = (unsigned*)alloc((size_t)E * 4);              // 6.4 MB
    unsigned*       pairs    = (unsigned*)alloc((size_t)E * 4);              // 6.4 MB
    int*            bin_counts = (int*)alloc(MAXB * 4);
    int*            bin_off    = (int*)alloc(MAXB * 4);
    int*            bin_cur    = (int*)alloc(MAXB * 4);
    unsigned short* wt1      = (unsigned short*)alloc((size_t)HID * K1 * 2);
    unsigned short* wt2      = (unsigned short*)alloc((size_t)HID * HID * 2);

    prep_kernel<<<(HID * K1 + 255) / 256, 256, 0, stream>>>(W1, W2, wt1, wt2, K1, bin_counts);

    const int ntiles = (E + TILE - 1) / TILE;
    bincount_kernel<<<ntiles, 256, 0, stream>>>(dstv, bin_counts, E, NB);
    binscan_kernel<<<1, 256, 0, stream>>>(bin_counts, bin_off, bin_cur, NB);
    stage_kernel<<<ntiles, 256, 0, stream>>>(srcv, dstv, bin_cur, pairs, E);
    binrowp_kernel<<<NB, 256, 0, stream>>>(pairs, bin_off, dinv, rowp, N, NB, E);
    fine_kernel<<<NB, 256, 0, stream>>>(pairs, bin_off, rowp, dinv, colv1, N, NB, E);

    gemm_kernel<false, 256><<<(N + 127) / 128, 256, 0, stream>>>((const void*)x, wt1, xw, N);
    agg1_kernel<<<(N + 3) / 4, 256, 0, stream>>>(xw, colv1, rowp, dinv,
                                                 b1, Wc, bc, (uint4*)h1, outp, N);
    gemm_kernel<true, 128><<<(N + 127) / 128, 256, 0, stream>>>((const void*)h1, wt2, xw, N);
    agg2_kernel<<<(N + 3) / 4, 256, 0, stream>>>(xw, (const uint4*)h1, colv1,
                                                 rowp, dinv, b2, Wf, bfv, hnode, outp, N);
}